// Round 11
// baseline (285.232 us; speedup 1.0000x reference)
//
#include <hip/hip_runtime.h>

#define DIM 128
constexpr float EPS = 1e-5f;
#define SHARD 2048  // 8 shards x 256 floats (sum[128] + sumsq[128]) per layer

typedef _Float16 f16;
typedef __attribute__((ext_vector_type(8))) _Float16 f16x8;
typedef __attribute__((ext_vector_type(4))) float f32x4;

// ---------------- prep: W split (blocks 0..11) + degree count (blocks 12..) ----------
__global__ __launch_bounds__(256) void k_prep(const int* __restrict__ dst,
                                              int* __restrict__ degi, int E,
                                              const float* __restrict__ W0,
                                              const float* __restrict__ W1,
                                              const float* __restrict__ W2,
                                              f16* __restrict__ wt) {
    if (blockIdx.x < 12) {
        int layer = blockIdx.x >> 2;
        int quarter = blockIdx.x & 3;
        const float* W = layer == 0 ? W0 : (layer == 1 ? W1 : W2);
        f16* hi = wt + (size_t)layer * 2 * DIM * DIM;
        f16* lo = hi + DIM * DIM;
        for (int idx = quarter * 4096 + threadIdx.x; idx < (quarter + 1) * 4096;
             idx += 256) {
            int k = idx >> 7, c = idx & 127;
            float w = W[idx];
            f16 h = (f16)w;
            f16 l = (f16)((w - (float)h) * 2048.0f);
            hi[c * DIM + k] = h;
            lo[c * DIM + k] = l;
        }
    } else {
        int e = (blockIdx.x - 12) * 256 + threadIdx.x;
        if (e < E) atomicAdd(&degi[dst[e]], 1);
    }
}

// ---------------- scan pass 1: block-local exclusive scan + fused dinv ----------------
__global__ __launch_bounds__(256) void k_scan_local(const int* __restrict__ degi,
                                                    int* __restrict__ row_ptr,
                                                    float* __restrict__ dinv,
                                                    int* __restrict__ bsum, int n) {
    __shared__ int ws[4];
    int t = threadIdx.x, lane = t & 63, wv = t >> 6;
    int i0 = blockIdx.x * 1024 + t * 4;
    int v[4];
#pragma unroll
    for (int j = 0; j < 4; ++j) {
        int i = i0 + j;
        v[j] = (i < n) ? degi[i] : 0;
        if (i < n) dinv[i] = rsqrtf((float)v[j] + 1.0f);
    }
    int tsum = v[0] + v[1] + v[2] + v[3];
    int sc = tsum;
#pragma unroll
    for (int off = 1; off < 64; off <<= 1) {
        int u = __shfl_up(sc, off, 64);
        if (lane >= off) sc += u;
    }
    if (lane == 63) ws[wv] = sc;
    __syncthreads();
    int woff = 0;
    for (int j = 0; j < wv; ++j) woff += ws[j];
    int run = woff + sc - tsum;
#pragma unroll
    for (int j = 0; j < 4; ++j) {
        int i = i0 + j;
        if (i < n) row_ptr[i] = run;
        run += v[j];
    }
    if (t == 255) bsum[blockIdx.x] = woff + sc;
}

// ---------------- scan pass 2: add block offsets (inline bsum scan), cursor init ------
__global__ __launch_bounds__(256) void k_scan_add(int* __restrict__ row_ptr,
                                                  int* __restrict__ cursor,
                                                  const int* __restrict__ bsum,
                                                  int n, int E, int nb) {
    __shared__ int soff;
    int t = threadIdx.x;
    int seg = blockIdx.x >> 2;
    if (t < 64) {
        int v = (t < nb) ? bsum[t] : 0;
        int sc = v;
#pragma unroll
        for (int off = 1; off < 64; off <<= 1) {
            int u = __shfl_up(sc, off, 64);
            if (t >= off) sc += u;
        }
        if (t == seg) soff = sc - v;
    }
    __syncthreads();
    int i = blockIdx.x * 256 + t;
    if (i < n) {
        int v = row_ptr[i] + soff;
        row_ptr[i] = v;
        cursor[i] = v;
    }
    if (i == 0) row_ptr[n] = E;
}

// ---------------- fill CSR: csr_src grouped by dst ----------------
__global__ void k_fill(const int* __restrict__ src, const int* __restrict__ dst,
                       int* __restrict__ cursor, int* __restrict__ csr_src, int E) {
    int e = blockIdx.x * blockDim.x + threadIdx.x;
    if (e >= E) return;
    int d = dst[e];
    int slot = atomicAdd(&cursor[d], 1);
    csr_src[slot] = src[e];
}

// ---------------- MFMA GEMM: fp16 A, fp16 hi/lo W (2 products) ----------------
template <bool PRE_BN>
__global__ __launch_bounds__(256) void k_matmul_mfma(
    const float* __restrict__ inF, const f16* __restrict__ inH,
    const f16* __restrict__ wt, const float* __restrict__ dinv,
    const float* __restrict__ stats, const float* __restrict__ g,
    const float* __restrict__ be, float inv_n, f16* __restrict__ out, int n) {
    __shared__ __align__(16) char sA[64 * 256];
    __shared__ float sScale[DIM], sShift[DIM];

    int t = threadIdx.x;
    int w = t >> 6, l = t & 63;
    int row0 = blockIdx.x * 64;

    if (PRE_BN) {
        if (t < DIM) {
            float su = 0.f, sq = 0.f;
#pragma unroll
            for (int s = 0; s < 8; ++s) {
                su += stats[s * 256 + t];
                sq += stats[s * 256 + 128 + t];
            }
            float mu = su * inv_n;
            float var = sq * inv_n - mu * mu;
            float sc = rsqrtf(var + EPS) * g[t];
            sScale[t] = sc;
            sShift[t] = be[t] - mu * sc;
        }
        __syncthreads();
    }

    // ---- W fragments (16B loads from transposed split) ----
    f16x8 bh[2][4], bl[2][4];
    {
        int col = w * 32 + (l & 15);
        int ksub = (l >> 4) * 8;
        const f16* hi = wt;
        const f16* lo = wt + DIM * DIM;
#pragma unroll
        for (int ct = 0; ct < 2; ++ct) {
            int c2 = col + ct * 16;
#pragma unroll
            for (int kt = 0; kt < 4; ++kt) {
                bh[ct][kt] = *(const f16x8*)&hi[(size_t)c2 * DIM + kt * 32 + ksub];
                bl[ct][kt] = *(const f16x8*)&lo[(size_t)c2 * DIM + kt * 32 + ksub];
            }
        }
    }

    // ---- stage A tile (64x128 fp16), XOR-swizzled ----
    {
        int r = t >> 2;
        int row_g = row0 + r;
        if (row_g >= n) row_g = n - 1;
        int cbase = (t & 3) * 32;
#pragma unroll
        for (int o = 0; o < 4; ++o) {
            int c0 = cbase + o * 8;
            f16x8 h8;
            if (PRE_BN) {
                f16x8 v8 = *(const f16x8*)(inH + (size_t)row_g * DIM + c0);
#pragma unroll
                for (int j = 0; j < 8; ++j) {
                    float v = (float)v8[j] * sScale[c0 + j] + sShift[c0 + j];
                    h8[j] = (f16)fmaxf(v, 0.f);
                }
            } else {
                float4 v0 = *(const float4*)(inF + (size_t)row_g * DIM + c0);
                float4 v1 = *(const float4*)(inF + (size_t)row_g * DIM + c0 + 4);
                h8[0] = (f16)v0.x; h8[1] = (f16)v0.y; h8[2] = (f16)v0.z; h8[3] = (f16)v0.w;
                h8[4] = (f16)v1.x; h8[5] = (f16)v1.y; h8[6] = (f16)v1.z; h8[7] = (f16)v1.w;
            }
            int byte = (r * 256 + c0 * 2) ^ ((r & 7) << 4);
            *(f16x8*)(sA + byte) = h8;
        }
    }
    __syncthreads();

    // ---- MFMA main: 2 products (W-hi, W-lo) ----
    f32x4 accA[4][2], accB[4][2];
#pragma unroll
    for (int rt = 0; rt < 4; ++rt)
#pragma unroll
        for (int ct = 0; ct < 2; ++ct) {
            accA[rt][ct] = (f32x4){0.f, 0.f, 0.f, 0.f};
            accB[rt][ct] = (f32x4){0.f, 0.f, 0.f, 0.f};
        }

#pragma unroll
    for (int rt = 0; rt < 4; ++rt) {
        int row_l = rt * 16 + (l & 15);
        int kb = (l >> 4) * 16;
        f16x8 a[4];
#pragma unroll
        for (int kt = 0; kt < 4; ++kt) {
            int byte = (row_l * 256 + kt * 64 + kb) ^ ((row_l & 7) << 4);
            a[kt] = *(const f16x8*)(sA + byte);
        }
#pragma unroll
        for (int ct = 0; ct < 2; ++ct) {
            f32x4 cA = accA[rt][ct], cB = accB[rt][ct];
#pragma unroll
            for (int kt = 0; kt < 4; ++kt) {
                cA = __builtin_amdgcn_mfma_f32_16x16x32_f16(a[kt], bh[ct][kt], cA, 0, 0, 0);
                cB = __builtin_amdgcn_mfma_f32_16x16x32_f16(a[kt], bl[ct][kt], cB, 0, 0, 0);
            }
            accA[rt][ct] = cA;
            accB[rt][ct] = cB;
        }
    }

    // ---- epilogue: combine, scale by dinv[row], store fp16 ----
    int colw = w * 32 + (l & 15);
#pragma unroll
    for (int rt = 0; rt < 4; ++rt) {
        int row_l = rt * 16 + ((l >> 4) << 2);
#pragma unroll
        for (int reg = 0; reg < 4; ++reg) {
            int gr = row0 + row_l + reg;
            if (gr >= n) continue;
            float dv = dinv[gr];
#pragma unroll
            for (int ct = 0; ct < 2; ++ct) {
                float v = (accA[rt][ct][reg] + accB[rt][ct][reg] * (1.0f / 2048.0f)) * dv;
                out[(size_t)gr * DIM + colw + ct * 16] = (f16)v;
            }
        }
    }
}

// ---------------- fused gather + BN stats (+ pool), wave-independent ----------------
// 256 thr = 4 waves; each WAVE owns a contiguous chunk of nodes. Stats in regs,
// one block-level LDS reduce at the end. Pool: per-wave reg accumulator, direct
// flush at graph boundaries, final open segment merged across block in LDS.
template <bool POOL>
__global__ __launch_bounds__(256) void k_gs(const f16* __restrict__ hs,
                                            const int* __restrict__ csr_src,
                                            const int* __restrict__ row_ptr,
                                            const float* __restrict__ dinv,
                                            const float* __restrict__ b,
                                            const int* __restrict__ batch,
                                            f16* __restrict__ agg,
                                            float* __restrict__ stats_part,
                                            float* __restrict__ gsum,
                                            int n, int chunk) {
    __shared__ float sred[4][256];
    __shared__ float sPool[4][DIM];
    __shared__ int sSegId[4];

    int t = threadIdx.x, wv = t >> 6, l = t & 63;
    int grp = l >> 4, c8 = (l & 15) * 8;
    int wid = blockIdx.x * 4 + wv;
    int r0 = wid * chunk;
    int r1 = min(n, r0 + chunk);

    float ssum[8] = {}, ssq[8] = {}, pacc[8] = {};
    int curseg = -1;
    int b0 = POOL ? batch[0] : 0;
    f32x4 bb0 = {0,0,0,0}, bb1 = {0,0,0,0};
    if (grp == 0) {
        bb0 = *(const f32x4*)(b + c8);
        bb1 = *(const f32x4*)(b + c8 + 4);
    }

    int beg = (r0 < r1) ? row_ptr[r0] : 0;
    for (int node = r0; node < r1; ++node) {
        int end = row_ptr[node + 1];
        float acc[8] = {};
        int e = beg + grp;
        for (; e + 4 < end; e += 8) {
            int s0 = csr_src[e];
            int s1 = csr_src[e + 4];
            f16x8 a = *(const f16x8*)(hs + (size_t)s0 * DIM + c8);
            f16x8 c = *(const f16x8*)(hs + (size_t)s1 * DIM + c8);
#pragma unroll
            for (int j = 0; j < 8; ++j) acc[j] += (float)a[j] + (float)c[j];
        }
        for (; e < end; e += 4) {
            int s0 = csr_src[e];
            f16x8 a = *(const f16x8*)(hs + (size_t)s0 * DIM + c8);
#pragma unroll
            for (int j = 0; j < 8; ++j) acc[j] += (float)a[j];
        }
#pragma unroll
        for (int j = 0; j < 8; ++j) {
            acc[j] += __shfl_xor(acc[j], 16, 64);
            acc[j] += __shfl_xor(acc[j], 32, 64);
        }
        if (grp == 0) {
            f16x8 hv = *(const f16x8*)(hs + (size_t)node * DIM + c8);
            float dv = dinv[node];
            float o[8];
#pragma unroll
            for (int j = 0; j < 4; ++j) {
                o[j] = (acc[j] + (float)hv[j]) * dv + bb0[j];
                o[j + 4] = (acc[j + 4] + (float)hv[j + 4]) * dv + bb1[j];
            }
            f16x8 ov;
#pragma unroll
            for (int j = 0; j < 8; ++j) ov[j] = (f16)o[j];
            *(f16x8*)(agg + (size_t)node * DIM + c8) = ov;
#pragma unroll
            for (int j = 0; j < 8; ++j) {
                ssum[j] += o[j];
                ssq[j] += o[j] * o[j];
            }
            if (POOL) {
                int seg = batch[node] - b0;
                if (seg != curseg) {
                    if (curseg >= 0) {
#pragma unroll
                        for (int j = 0; j < 8; ++j)
                            atomicAdd(&gsum[(size_t)curseg * DIM + c8 + j], pacc[j]);
                    }
#pragma unroll
                    for (int j = 0; j < 8; ++j) pacc[j] = 0.f;
                    curseg = seg;
                }
#pragma unroll
                for (int j = 0; j < 8; ++j) pacc[j] += o[j];
            }
        }
        beg = end;
    }

    // ---- block-level stats reduce + (POOL) final-segment merge ----
    if (grp == 0) {
#pragma unroll
        for (int j = 0; j < 8; ++j) {
            sred[wv][c8 + j] = ssum[j];
            sred[wv][128 + c8 + j] = ssq[j];
        }
        if (POOL) {
#pragma unroll
            for (int j = 0; j < 8; ++j) sPool[wv][c8 + j] = pacc[j];
            if (l == 0) sSegId[wv] = curseg;
        }
    }
    __syncthreads();
    float s = sred[0][t] + sred[1][t] + sred[2][t] + sred[3][t];
    atomicAdd(&stats_part[(blockIdx.x & 7) * 256 + t], s);
    if (POOL && t < 128) {
        int cur = -1;
        float a = 0.f;
        for (int w = 0; w < 4; ++w) {
            int sg = sSegId[w];
            if (sg < 0) continue;
            if (sg != cur) {
                if (cur >= 0) atomicAdd(&gsum[(size_t)cur * DIM + t], a);
                a = 0.f;
                cur = sg;
            }
            a += sPool[w][t];
        }
        if (cur >= 0) atomicAdd(&gsum[(size_t)cur * DIM + t], a);
    }
}

// ---------------- pool finalize: out = mean*scale + shift ----------------
__global__ __launch_bounds__(128) void k_pool_fin(const float* __restrict__ gsum,
                                                  const int* __restrict__ batch,
                                                  const float* __restrict__ stats,
                                                  const float* __restrict__ g,
                                                  const float* __restrict__ be,
                                                  float* __restrict__ out,
                                                  int n, float inv_n) {
    int gseg = blockIdx.x;
    int c = threadIdx.x;
    int b0 = batch[0];
    int target = b0 + gseg;
    int lo = 0, hi = n;
    while (lo < hi) { int mid = (lo + hi) >> 1; if (batch[mid] < target) lo = mid + 1; else hi = mid; }
    int start = lo;
    lo = start; hi = n;
    while (lo < hi) { int mid = (lo + hi) >> 1; if (batch[mid] < target + 1) lo = mid + 1; else hi = mid; }
    int end = lo;
    int cnt = end - start;

    float su = 0.f, sq = 0.f;
#pragma unroll
    for (int s = 0; s < 8; ++s) {
        su += stats[s * 256 + c];
        sq += stats[s * 256 + 128 + c];
    }
    float mu = su * inv_n;
    float var = sq * inv_n - mu * mu;
    float scale = rsqrtf(var + EPS) * g[c];
    float shift = be[c] - mu * scale;
    float o = 0.f;
    if (cnt > 0) o = (gsum[(size_t)gseg * DIM + c] / (float)cnt) * scale + shift;
    out[(size_t)gseg * DIM + c] = o;
}

// ---------------- launch ----------------
extern "C" void kernel_launch(void* const* d_in, const int* in_sizes, int n_in,
                              void* d_out, int out_size, void* d_ws, size_t ws_size,
                              hipStream_t stream) {
    const float* x = (const float*)d_in[0];
    const int* edge_index = (const int*)d_in[1];
    const int* batch = (const int*)d_in[3];
    const float* W1 = (const float*)d_in[4];
    const float* b1 = (const float*)d_in[5];
    const float* g1 = (const float*)d_in[6];
    const float* be1 = (const float*)d_in[7];
    const float* Wm = (const float*)d_in[8];
    const float* bm = (const float*)d_in[9];
    const float* gm = (const float*)d_in[10];
    const float* bem = (const float*)d_in[11];
    const float* W2 = (const float*)d_in[12];
    const float* b2 = (const float*)d_in[13];
    const float* g2 = (const float*)d_in[14];
    const float* be2 = (const float*)d_in[15];

    int n = in_sizes[0] / DIM;
    int E = in_sizes[1] / 2;
    int G = out_size / DIM;

    const int* srcI = edge_index;
    const int* dstI = edge_index + E;

    char* p = (char*)d_ws;
    f16* bufA = (f16*)p;                p += (size_t)n * DIM * 2;   // hs fp16
    f16* bufB = (f16*)p;                p += (size_t)n * DIM * 2;   // agg fp16
    float* dinv = (float*)p;            p += (size_t)n * 4;
    int* row_ptr = (int*)p;             p += (size_t)(n + 1) * 4;
    int* cursor = (int*)p;              p += (size_t)n * 4;
    int* csr_src = (int*)p;             p += (size_t)E * 4;
    int* bsum = (int*)p;                p += 64 * 4;
    // ---- contiguous zero region ----
    char* zero0 = p;
    int* degi = (int*)p;                p += (size_t)n * 4;
    float* stats3 = (float*)p;          p += 3 * SHARD * 4;
    float* gsum = (float*)p;            p += (size_t)G * DIM * 4;
    size_t zero_bytes = (size_t)(p - zero0);
    // ---- W split buffer ----
    f16* wsplit = (f16*)p;              p += (size_t)3 * 2 * DIM * DIM * 2;

    float* out = (float*)d_out;
    float inv_n = 1.0f / (float)n;
    int nb = (n + 1023) / 1024;  // <= 64 assumed

    // ---- init + CSR build + W split ----
    hipMemsetAsync(zero0, 0, zero_bytes, stream);
    k_prep<<<12 + (E + 255) / 256, 256, 0, stream>>>(dstI, degi, E, W1, Wm, W2, wsplit);
    k_scan_local<<<nb, 256, 0, stream>>>(degi, row_ptr, dinv, bsum, n);
    k_scan_add<<<(n + 255) / 256, 256, 0, stream>>>(row_ptr, cursor, bsum, n, E, nb);
    k_fill<<<(E + 255) / 256, 256, 0, stream>>>(srcI, dstI, cursor, csr_src, E);

    struct Layer { const float *b, *g, *be; };
    Layer L[3] = {{b1, g1, be1}, {bm, gm, bem}, {b2, g2, be2}};

    int mmBlocks = (n + 63) / 64;
    const int CHUNK = 8;
    int gsBlocks = (n + 4 * CHUNK - 1) / (4 * CHUNK);
    for (int l = 0; l < 3; ++l) {
        const f16* wl = wsplit + (size_t)l * 2 * DIM * DIM;
        float* stats_l = stats3 + l * SHARD;
        if (l == 0)
            k_matmul_mfma<false><<<mmBlocks, 256, 0, stream>>>(
                x, nullptr, wl, dinv, nullptr, nullptr, nullptr, inv_n, bufA, n);
        else
            k_matmul_mfma<true><<<mmBlocks, 256, 0, stream>>>(
                nullptr, bufB, wl, dinv, stats3 + (l - 1) * SHARD,
                L[l - 1].g, L[l - 1].be, inv_n, bufA, n);
        if (l < 2)
            k_gs<false><<<gsBlocks, 256, 0, stream>>>(bufA, csr_src, row_ptr, dinv,
                                                      L[l].b, batch, bufB, stats_l,
                                                      nullptr, n, CHUNK);
        else
            k_gs<true><<<gsBlocks, 256, 0, stream>>>(bufA, csr_src, row_ptr, dinv,
                                                     L[l].b, batch, bufB, stats_l,
                                                     gsum, n, CHUNK);
    }

    // pool finalize: mean -> final BN affine
    k_pool_fin<<<G, 128, 0, stream>>>(gsum, batch, stats3 + 2 * SHARD, g2, be2,
                                      out, n, inv_n);
}

// Round 12
// 271.987 us; speedup vs baseline: 1.0487x; 1.0487x over previous
//
#include <hip/hip_runtime.h>

#define DIM 128
constexpr float EPS = 1e-5f;
#define SHARD 2048  // 8 shards x 256 floats (sum[128] + sumsq[128]) per layer

typedef _Float16 f16;
typedef __attribute__((ext_vector_type(8))) _Float16 f16x8;
typedef __attribute__((ext_vector_type(4))) float f32x4;

// ---------------- prep: W split (blocks 0..11) + degree count (blocks 12..) ----------
__global__ __launch_bounds__(256) void k_prep(const int* __restrict__ dst,
                                              int* __restrict__ degi, int E,
                                              const float* __restrict__ W0,
                                              const float* __restrict__ W1,
                                              const float* __restrict__ W2,
                                              f16* __restrict__ wt) {
    if (blockIdx.x < 12) {
        int layer = blockIdx.x >> 2;
        int quarter = blockIdx.x & 3;
        const float* W = layer == 0 ? W0 : (layer == 1 ? W1 : W2);
        f16* hi = wt + (size_t)layer * 2 * DIM * DIM;
        f16* lo = hi + DIM * DIM;
        for (int idx = quarter * 4096 + threadIdx.x; idx < (quarter + 1) * 4096;
             idx += 256) {
            int k = idx >> 7, c = idx & 127;
            float w = W[idx];
            f16 h = (f16)w;
            f16 l = (f16)((w - (float)h) * 2048.0f);
            hi[c * DIM + k] = h;
            lo[c * DIM + k] = l;
        }
    } else {
        int e = (blockIdx.x - 12) * 256 + threadIdx.x;
        if (e < E) atomicAdd(&degi[dst[e]], 1);
    }
}

// ---------------- scan pass 1: block-local exclusive scan + fused dinv ----------------
__global__ __launch_bounds__(256) void k_scan_local(const int* __restrict__ degi,
                                                    int* __restrict__ row_ptr,
                                                    float* __restrict__ dinv,
                                                    int* __restrict__ bsum, int n) {
    __shared__ int ws[4];
    int t = threadIdx.x, lane = t & 63, wv = t >> 6;
    int i0 = blockIdx.x * 1024 + t * 4;
    int v[4];
#pragma unroll
    for (int j = 0; j < 4; ++j) {
        int i = i0 + j;
        v[j] = (i < n) ? degi[i] : 0;
        if (i < n) dinv[i] = rsqrtf((float)v[j] + 1.0f);
    }
    int tsum = v[0] + v[1] + v[2] + v[3];
    int sc = tsum;
#pragma unroll
    for (int off = 1; off < 64; off <<= 1) {
        int u = __shfl_up(sc, off, 64);
        if (lane >= off) sc += u;
    }
    if (lane == 63) ws[wv] = sc;
    __syncthreads();
    int woff = 0;
    for (int j = 0; j < wv; ++j) woff += ws[j];
    int run = woff + sc - tsum;
#pragma unroll
    for (int j = 0; j < 4; ++j) {
        int i = i0 + j;
        if (i < n) row_ptr[i] = run;
        run += v[j];
    }
    if (t == 255) bsum[blockIdx.x] = woff + sc;
}

// ---------------- scan pass 2: add block offsets (inline bsum scan), cursor init ------
__global__ __launch_bounds__(256) void k_scan_add(int* __restrict__ row_ptr,
                                                  int* __restrict__ cursor,
                                                  const int* __restrict__ bsum,
                                                  int n, int E, int nb) {
    __shared__ int soff;
    int t = threadIdx.x;
    int seg = blockIdx.x >> 2;
    if (t < 64) {
        int v = (t < nb) ? bsum[t] : 0;
        int sc = v;
#pragma unroll
        for (int off = 1; off < 64; off <<= 1) {
            int u = __shfl_up(sc, off, 64);
            if (t >= off) sc += u;
        }
        if (t == seg) soff = sc - v;
    }
    __syncthreads();
    int i = blockIdx.x * 256 + t;
    if (i < n) {
        int v = row_ptr[i] + soff;
        row_ptr[i] = v;
        cursor[i] = v;
    }
    if (i == 0) row_ptr[n] = E;
}

// ---------------- fill CSR: csr_src grouped by dst ----------------
__global__ void k_fill(const int* __restrict__ src, const int* __restrict__ dst,
                       int* __restrict__ cursor, int* __restrict__ csr_src, int E) {
    int e = blockIdx.x * blockDim.x + threadIdx.x;
    if (e >= E) return;
    int d = dst[e];
    int slot = atomicAdd(&cursor[d], 1);
    csr_src[slot] = src[e];
}

// ---------------- MFMA GEMM: fp16 A, fp16 hi/lo W (2 products) ----------------
template <bool PRE_BN>
__global__ __launch_bounds__(256) void k_matmul_mfma(
    const float* __restrict__ inF, const f16* __restrict__ inH,
    const f16* __restrict__ wt, const float* __restrict__ dinv,
    const float* __restrict__ stats, const float* __restrict__ g,
    const float* __restrict__ be, float inv_n, f16* __restrict__ out, int n) {
    __shared__ __align__(16) char sA[64 * 256];
    __shared__ float sScale[DIM], sShift[DIM];

    int t = threadIdx.x;
    int w = t >> 6, l = t & 63;
    int row0 = blockIdx.x * 64;

    if (PRE_BN) {
        if (t < DIM) {
            float su = 0.f, sq = 0.f;
#pragma unroll
            for (int s = 0; s < 8; ++s) {
                su += stats[s * 256 + t];
                sq += stats[s * 256 + 128 + t];
            }
            float mu = su * inv_n;
            float var = sq * inv_n - mu * mu;
            float sc = rsqrtf(var + EPS) * g[t];
            sScale[t] = sc;
            sShift[t] = be[t] - mu * sc;
        }
        __syncthreads();
    }

    // ---- W fragments (16B loads from transposed split) ----
    f16x8 bh[2][4], bl[2][4];
    {
        int col = w * 32 + (l & 15);
        int ksub = (l >> 4) * 8;
        const f16* hi = wt;
        const f16* lo = wt + DIM * DIM;
#pragma unroll
        for (int ct = 0; ct < 2; ++ct) {
            int c2 = col + ct * 16;
#pragma unroll
            for (int kt = 0; kt < 4; ++kt) {
                bh[ct][kt] = *(const f16x8*)&hi[(size_t)c2 * DIM + kt * 32 + ksub];
                bl[ct][kt] = *(const f16x8*)&lo[(size_t)c2 * DIM + kt * 32 + ksub];
            }
        }
    }

    // ---- stage A tile (64x128 fp16), XOR-swizzled ----
    {
        int r = t >> 2;
        int row_g = row0 + r;
        if (row_g >= n) row_g = n - 1;
        int cbase = (t & 3) * 32;
#pragma unroll
        for (int o = 0; o < 4; ++o) {
            int c0 = cbase + o * 8;
            f16x8 h8;
            if (PRE_BN) {
                f16x8 v8 = *(const f16x8*)(inH + (size_t)row_g * DIM + c0);
#pragma unroll
                for (int j = 0; j < 8; ++j) {
                    float v = (float)v8[j] * sScale[c0 + j] + sShift[c0 + j];
                    h8[j] = (f16)fmaxf(v, 0.f);
                }
            } else {
                float4 v0 = *(const float4*)(inF + (size_t)row_g * DIM + c0);
                float4 v1 = *(const float4*)(inF + (size_t)row_g * DIM + c0 + 4);
                h8[0] = (f16)v0.x; h8[1] = (f16)v0.y; h8[2] = (f16)v0.z; h8[3] = (f16)v0.w;
                h8[4] = (f16)v1.x; h8[5] = (f16)v1.y; h8[6] = (f16)v1.z; h8[7] = (f16)v1.w;
            }
            int byte = (r * 256 + c0 * 2) ^ ((r & 7) << 4);
            *(f16x8*)(sA + byte) = h8;
        }
    }
    __syncthreads();

    // ---- MFMA main: 2 products (W-hi, W-lo) ----
    f32x4 accA[4][2], accB[4][2];
#pragma unroll
    for (int rt = 0; rt < 4; ++rt)
#pragma unroll
        for (int ct = 0; ct < 2; ++ct) {
            accA[rt][ct] = (f32x4){0.f, 0.f, 0.f, 0.f};
            accB[rt][ct] = (f32x4){0.f, 0.f, 0.f, 0.f};
        }

#pragma unroll
    for (int rt = 0; rt < 4; ++rt) {
        int row_l = rt * 16 + (l & 15);
        int kb = (l >> 4) * 16;
        f16x8 a[4];
#pragma unroll
        for (int kt = 0; kt < 4; ++kt) {
            int byte = (row_l * 256 + kt * 64 + kb) ^ ((row_l & 7) << 4);
            a[kt] = *(const f16x8*)(sA + byte);
        }
#pragma unroll
        for (int ct = 0; ct < 2; ++ct) {
            f32x4 cA = accA[rt][ct], cB = accB[rt][ct];
#pragma unroll
            for (int kt = 0; kt < 4; ++kt) {
                cA = __builtin_amdgcn_mfma_f32_16x16x32_f16(a[kt], bh[ct][kt], cA, 0, 0, 0);
                cB = __builtin_amdgcn_mfma_f32_16x16x32_f16(a[kt], bl[ct][kt], cB, 0, 0, 0);
            }
            accA[rt][ct] = cA;
            accB[rt][ct] = cB;
        }
    }

    // ---- epilogue: combine, scale by dinv[row], store fp16 ----
    int colw = w * 32 + (l & 15);
#pragma unroll
    for (int rt = 0; rt < 4; ++rt) {
        int row_l = rt * 16 + ((l >> 4) << 2);
#pragma unroll
        for (int reg = 0; reg < 4; ++reg) {
            int gr = row0 + row_l + reg;
            if (gr >= n) continue;
            float dv = dinv[gr];
#pragma unroll
            for (int ct = 0; ct < 2; ++ct) {
                float v = (accA[rt][ct][reg] + accB[rt][ct][reg] * (1.0f / 2048.0f)) * dv;
                out[(size_t)gr * DIM + colw + ct * 16] = (f16)v;
            }
        }
    }
}

// ---------------- fused gather + BN stats (+ pool): 16 waves = 16 nodes/block --------
// Wave-per-node (max wave parallelism) with 4-deep predicated edge batch:
// edges e, e+4, e+8, e+12 issue before any use -> deg<=16 node = 1 mem round trip.
template <bool POOL>
__global__ __launch_bounds__(1024) void k_gs(const f16* __restrict__ hs,
                                             const int* __restrict__ csr_src,
                                             const int* __restrict__ row_ptr,
                                             const float* __restrict__ dinv,
                                             const float* __restrict__ b,
                                             const int* __restrict__ batch,
                                             f16* __restrict__ agg,
                                             float* __restrict__ stats_part,
                                             float* __restrict__ gsum, int n) {
    __shared__ float sSum[16][DIM];
    __shared__ float sSq[16][DIM];
    __shared__ int sSeg[16];

    int t = threadIdx.x;
    int wv = t >> 6, l = t & 63;
    int node = blockIdx.x * 16 + wv;
    int grp = l >> 4;
    int c8 = (l & 15) * 8;
    bool valid = node < n;

    float acc[8] = {};
    int beg = 0, end = 0;
    if (valid) {
        beg = row_ptr[node];
        end = row_ptr[node + 1];
    }
    // 4-deep predicated batch: all loads issue, then accumulate.
    for (int e = beg + grp; e < end; e += 16) {
        bool v1 = e + 4 < end, v2 = e + 8 < end, v3 = e + 12 < end;
        f16x8 a0 = *(const f16x8*)(hs + (size_t)csr_src[e] * DIM + c8);
        f16x8 a1 = {}, a2 = {}, a3 = {};
        if (v1) a1 = *(const f16x8*)(hs + (size_t)csr_src[e + 4] * DIM + c8);
        if (v2) a2 = *(const f16x8*)(hs + (size_t)csr_src[e + 8] * DIM + c8);
        if (v3) a3 = *(const f16x8*)(hs + (size_t)csr_src[e + 12] * DIM + c8);
#pragma unroll
        for (int j = 0; j < 8; ++j)
            acc[j] += ((float)a0[j] + (float)a1[j]) + ((float)a2[j] + (float)a3[j]);
    }
#pragma unroll
    for (int j = 0; j < 8; ++j) {
        acc[j] += __shfl_xor(acc[j], 16, 64);
        acc[j] += __shfl_xor(acc[j], 32, 64);
    }

    if (grp == 0) {
        if (valid) {
            f16x8 hv = *(const f16x8*)(hs + (size_t)node * DIM + c8);
            float dv = dinv[node];
            f32x4 bb0 = *(const f32x4*)(b + c8);
            f32x4 bb1 = *(const f32x4*)(b + c8 + 4);
            float o[8];
#pragma unroll
            for (int j = 0; j < 4; ++j) {
                o[j] = (acc[j] + (float)hv[j]) * dv + bb0[j];
                o[j + 4] = (acc[j + 4] + (float)hv[j + 4]) * dv + bb1[j];
            }
            f16x8 ov;
#pragma unroll
            for (int j = 0; j < 8; ++j) ov[j] = (f16)o[j];
            *(f16x8*)(agg + (size_t)node * DIM + c8) = ov;
            f32x4 s0 = {o[0], o[1], o[2], o[3]}, s1 = {o[4], o[5], o[6], o[7]};
            f32x4 q0 = {o[0]*o[0], o[1]*o[1], o[2]*o[2], o[3]*o[3]};
            f32x4 q1 = {o[4]*o[4], o[5]*o[5], o[6]*o[6], o[7]*o[7]};
            *(f32x4*)&sSum[wv][c8] = s0;
            *(f32x4*)&sSum[wv][c8 + 4] = s1;
            *(f32x4*)&sSq[wv][c8] = q0;
            *(f32x4*)&sSq[wv][c8 + 4] = q1;
            if (POOL && l == 0) sSeg[wv] = batch[node] - batch[0];
        } else {
            f32x4 z = {0.f, 0.f, 0.f, 0.f};
            *(f32x4*)&sSum[wv][c8] = z;
            *(f32x4*)&sSum[wv][c8 + 4] = z;
            *(f32x4*)&sSq[wv][c8] = z;
            *(f32x4*)&sSq[wv][c8 + 4] = z;
        }
    }
    __syncthreads();

    int shard = (blockIdx.x & 7) * 256;
    if (t < 128) {
        float s = 0.f;
#pragma unroll
        for (int w = 0; w < 16; ++w) s += sSum[w][t];
        atomicAdd(&stats_part[shard + t], s);
    } else if (t < 256) {
        int ch = t - 128;
        float s = 0.f;
#pragma unroll
        for (int w = 0; w < 16; ++w) s += sSq[w][ch];
        atomicAdd(&stats_part[shard + 128 + ch], s);
    }

    if (POOL && t < 128) {
        int cur = -1;
        float a = 0.f;
        for (int w = 0; w < 16; ++w) {
            if (blockIdx.x * 16 + w >= n) break;
            int seg = sSeg[w];
            if (seg != cur) {
                if (cur >= 0) atomicAdd(&gsum[(size_t)cur * DIM + t], a);
                a = 0.f;
                cur = seg;
            }
            a += sSum[w][t];
        }
        if (cur >= 0) atomicAdd(&gsum[(size_t)cur * DIM + t], a);
    }
}

// ---------------- pool finalize: out = mean*scale + shift ----------------
__global__ __launch_bounds__(128) void k_pool_fin(const float* __restrict__ gsum,
                                                  const int* __restrict__ batch,
                                                  const float* __restrict__ stats,
                                                  const float* __restrict__ g,
                                                  const float* __restrict__ be,
                                                  float* __restrict__ out,
                                                  int n, float inv_n) {
    int gseg = blockIdx.x;
    int c = threadIdx.x;
    int b0 = batch[0];
    int target = b0 + gseg;
    int lo = 0, hi = n;
    while (lo < hi) { int mid = (lo + hi) >> 1; if (batch[mid] < target) lo = mid + 1; else hi = mid; }
    int start = lo;
    lo = start; hi = n;
    while (lo < hi) { int mid = (lo + hi) >> 1; if (batch[mid] < target + 1) lo = mid + 1; else hi = mid; }
    int end = lo;
    int cnt = end - start;

    float su = 0.f, sq = 0.f;
#pragma unroll
    for (int s = 0; s < 8; ++s) {
        su += stats[s * 256 + c];
        sq += stats[s * 256 + 128 + c];
    }
    float mu = su * inv_n;
    float var = sq * inv_n - mu * mu;
    float scale = rsqrtf(var + EPS) * g[c];
    float shift = be[c] - mu * scale;
    float o = 0.f;
    if (cnt > 0) o = (gsum[(size_t)gseg * DIM + c] / (float)cnt) * scale + shift;
    out[(size_t)gseg * DIM + c] = o;
}

// ---------------- launch ----------------
extern "C" void kernel_launch(void* const* d_in, const int* in_sizes, int n_in,
                              void* d_out, int out_size, void* d_ws, size_t ws_size,
                              hipStream_t stream) {
    const float* x = (const float*)d_in[0];
    const int* edge_index = (const int*)d_in[1];
    const int* batch = (const int*)d_in[3];
    const float* W1 = (const float*)d_in[4];
    const float* b1 = (const float*)d_in[5];
    const float* g1 = (const float*)d_in[6];
    const float* be1 = (const float*)d_in[7];
    const float* Wm = (const float*)d_in[8];
    const float* bm = (const float*)d_in[9];
    const float* gm = (const float*)d_in[10];
    const float* bem = (const float*)d_in[11];
    const float* W2 = (const float*)d_in[12];
    const float* b2 = (const float*)d_in[13];
    const float* g2 = (const float*)d_in[14];
    const float* be2 = (const float*)d_in[15];

    int n = in_sizes[0] / DIM;
    int E = in_sizes[1] / 2;
    int G = out_size / DIM;

    const int* srcI = edge_index;
    const int* dstI = edge_index + E;

    char* p = (char*)d_ws;
    f16* bufA = (f16*)p;                p += (size_t)n * DIM * 2;   // hs fp16
    f16* bufB = (f16*)p;                p += (size_t)n * DIM * 2;   // agg fp16
    float* dinv = (float*)p;            p += (size_t)n * 4;
    int* row_ptr = (int*)p;             p += (size_t)(n + 1) * 4;
    int* cursor = (int*)p;              p += (size_t)n * 4;
    int* csr_src = (int*)p;             p += (size_t)E * 4;
    int* bsum = (int*)p;                p += 64 * 4;
    // ---- contiguous zero region ----
    char* zero0 = p;
    int* degi = (int*)p;                p += (size_t)n * 4;
    float* stats3 = (float*)p;          p += 3 * SHARD * 4;
    float* gsum = (float*)p;            p += (size_t)G * DIM * 4;
    size_t zero_bytes = (size_t)(p - zero0);
    // ---- W split buffer ----
    f16* wsplit = (f16*)p;              p += (size_t)3 * 2 * DIM * DIM * 2;

    float* out = (float*)d_out;
    float inv_n = 1.0f / (float)n;
    int nb = (n + 1023) / 1024;  // <= 64 assumed

    // ---- init + CSR build + W split ----
    hipMemsetAsync(zero0, 0, zero_bytes, stream);
    k_prep<<<12 + (E + 255) / 256, 256, 0, stream>>>(dstI, degi, E, W1, Wm, W2, wsplit);
    k_scan_local<<<nb, 256, 0, stream>>>(degi, row_ptr, dinv, bsum, n);
    k_scan_add<<<(n + 255) / 256, 256, 0, stream>>>(row_ptr, cursor, bsum, n, E, nb);
    k_fill<<<(E + 255) / 256, 256, 0, stream>>>(srcI, dstI, cursor, csr_src, E);

    struct Layer { const float *b, *g, *be; };
    Layer L[3] = {{b1, g1, be1}, {bm, gm, bem}, {b2, g2, be2}};

    int mmBlocks = (n + 63) / 64;
    int gsBlocks = (n + 15) / 16;
    for (int l = 0; l < 3; ++l) {
        const f16* wl = wsplit + (size_t)l * 2 * DIM * DIM;
        float* stats_l = stats3 + l * SHARD;
        if (l == 0)
            k_matmul_mfma<false><<<mmBlocks, 256, 0, stream>>>(
                x, nullptr, wl, dinv, nullptr, nullptr, nullptr, inv_n, bufA, n);
        else
            k_matmul_mfma<true><<<mmBlocks, 256, 0, stream>>>(
                nullptr, bufB, wl, dinv, stats3 + (l - 1) * SHARD,
                L[l - 1].g, L[l - 1].be, inv_n, bufA, n);
        if (l < 2)
            k_gs<false><<<gsBlocks, 1024, 0, stream>>>(bufA, csr_src, row_ptr, dinv,
                                                       L[l].b, batch, bufB, stats_l,
                                                       nullptr, n);
        else
            k_gs<true><<<gsBlocks, 1024, 0, stream>>>(bufA, csr_src, row_ptr, dinv,
                                                      L[l].b, batch, bufB, stats_l,
                                                      gsum, n);
    }

    // pool finalize: mean -> final BN affine
    k_pool_fin<<<G, 128, 0, stream>>>(gsum, batch, stats3 + 2 * SHARD, g2, be2,
                                      out, n, inv_n);
}

// Round 13
// 268.503 us; speedup vs baseline: 1.0623x; 1.0130x over previous
//
#include <hip/hip_runtime.h>

#define DIM 128
constexpr float EPS = 1e-5f;
#define NSHARD 32
#define SHARD (NSHARD * 256)  // floats per layer: 32 shards x (sum[128]+sumsq[128])

typedef _Float16 f16;
typedef __attribute__((ext_vector_type(8))) _Float16 f16x8;
typedef __attribute__((ext_vector_type(4))) float f32x4;

// ---------------- prep: W split (blocks 0..11) + degree count (blocks 12..) ----------
__global__ __launch_bounds__(256) void k_prep(const int* __restrict__ dst,
                                              int* __restrict__ degi, int E,
                                              const float* __restrict__ W0,
                                              const float* __restrict__ W1,
                                              const float* __restrict__ W2,
                                              f16* __restrict__ wt) {
    if (blockIdx.x < 12) {
        int layer = blockIdx.x >> 2;
        int quarter = blockIdx.x & 3;
        const float* W = layer == 0 ? W0 : (layer == 1 ? W1 : W2);
        f16* hi = wt + (size_t)layer * 2 * DIM * DIM;
        f16* lo = hi + DIM * DIM;
        for (int idx = quarter * 4096 + threadIdx.x; idx < (quarter + 1) * 4096;
             idx += 256) {
            int k = idx >> 7, c = idx & 127;
            float w = W[idx];
            f16 h = (f16)w;
            f16 l = (f16)((w - (float)h) * 2048.0f);
            hi[c * DIM + k] = h;
            lo[c * DIM + k] = l;
        }
    } else {
        int e = (blockIdx.x - 12) * 256 + threadIdx.x;
        if (e < E) atomicAdd(&degi[dst[e]], 1);
    }
}

// ---------------- scan pass 1: block-local exclusive scan + fused dinv ----------------
__global__ __launch_bounds__(256) void k_scan_local(const int* __restrict__ degi,
                                                    int* __restrict__ row_ptr,
                                                    float* __restrict__ dinv,
                                                    int* __restrict__ bsum, int n) {
    __shared__ int ws[4];
    int t = threadIdx.x, lane = t & 63, wv = t >> 6;
    int i0 = blockIdx.x * 1024 + t * 4;
    int v[4];
#pragma unroll
    for (int j = 0; j < 4; ++j) {
        int i = i0 + j;
        v[j] = (i < n) ? degi[i] : 0;
        if (i < n) dinv[i] = rsqrtf((float)v[j] + 1.0f);
    }
    int tsum = v[0] + v[1] + v[2] + v[3];
    int sc = tsum;
#pragma unroll
    for (int off = 1; off < 64; off <<= 1) {
        int u = __shfl_up(sc, off, 64);
        if (lane >= off) sc += u;
    }
    if (lane == 63) ws[wv] = sc;
    __syncthreads();
    int woff = 0;
    for (int j = 0; j < wv; ++j) woff += ws[j];
    int run = woff + sc - tsum;
#pragma unroll
    for (int j = 0; j < 4; ++j) {
        int i = i0 + j;
        if (i < n) row_ptr[i] = run;
        run += v[j];
    }
    if (t == 255) bsum[blockIdx.x] = woff + sc;
}

// ---------------- scan pass 2: add block offsets (inline bsum scan), cursor init ------
__global__ __launch_bounds__(256) void k_scan_add(int* __restrict__ row_ptr,
                                                  int* __restrict__ cursor,
                                                  const int* __restrict__ bsum,
                                                  int n, int E, int nb) {
    __shared__ int soff;
    int t = threadIdx.x;
    int seg = blockIdx.x >> 2;
    if (t < 64) {
        int v = (t < nb) ? bsum[t] : 0;
        int sc = v;
#pragma unroll
        for (int off = 1; off < 64; off <<= 1) {
            int u = __shfl_up(sc, off, 64);
            if (t >= off) sc += u;
        }
        if (t == seg) soff = sc - v;
    }
    __syncthreads();
    int i = blockIdx.x * 256 + t;
    if (i < n) {
        int v = row_ptr[i] + soff;
        row_ptr[i] = v;
        cursor[i] = v;
    }
    if (i == 0) row_ptr[n] = E;
}

// ---------------- fill CSR: csr_src grouped by dst ----------------
__global__ void k_fill(const int* __restrict__ src, const int* __restrict__ dst,
                       int* __restrict__ cursor, int* __restrict__ csr_src, int E) {
    int e = blockIdx.x * blockDim.x + threadIdx.x;
    if (e >= E) return;
    int d = dst[e];
    int slot = atomicAdd(&cursor[d], 1);
    csr_src[slot] = src[e];
}

// ---------------- MFMA GEMM: fp16 A, fp16 hi/lo W (2 products) ----------------
template <bool PRE_BN>
__global__ __launch_bounds__(256) void k_matmul_mfma(
    const float* __restrict__ inF, const f16* __restrict__ inH,
    const f16* __restrict__ wt, const float* __restrict__ dinv,
    const float* __restrict__ stats, const float* __restrict__ g,
    const float* __restrict__ be, float inv_n, f16* __restrict__ out, int n) {
    __shared__ __align__(16) char sA[64 * 256];
    __shared__ float sScale[DIM], sShift[DIM];

    int t = threadIdx.x;
    int w = t >> 6, l = t & 63;
    int row0 = blockIdx.x * 64;

    if (PRE_BN) {
        if (t < DIM) {
            float su = 0.f, sq = 0.f;
            for (int s = 0; s < NSHARD; ++s) {
                su += stats[s * 256 + t];
                sq += stats[s * 256 + 128 + t];
            }
            float mu = su * inv_n;
            float var = sq * inv_n - mu * mu;
            float sc = rsqrtf(var + EPS) * g[t];
            sScale[t] = sc;
            sShift[t] = be[t] - mu * sc;
        }
        __syncthreads();
    }

    // ---- W fragments (16B loads from transposed split) ----
    f16x8 bh[2][4], bl[2][4];
    {
        int col = w * 32 + (l & 15);
        int ksub = (l >> 4) * 8;
        const f16* hi = wt;
        const f16* lo = wt + DIM * DIM;
#pragma unroll
        for (int ct = 0; ct < 2; ++ct) {
            int c2 = col + ct * 16;
#pragma unroll
            for (int kt = 0; kt < 4; ++kt) {
                bh[ct][kt] = *(const f16x8*)&hi[(size_t)c2 * DIM + kt * 32 + ksub];
                bl[ct][kt] = *(const f16x8*)&lo[(size_t)c2 * DIM + kt * 32 + ksub];
            }
        }
    }

    // ---- stage A tile (64x128 fp16), XOR-swizzled ----
    {
        int r = t >> 2;
        int row_g = row0 + r;
        if (row_g >= n) row_g = n - 1;
        int cbase = (t & 3) * 32;
#pragma unroll
        for (int o = 0; o < 4; ++o) {
            int c0 = cbase + o * 8;
            f16x8 h8;
            if (PRE_BN) {
                f16x8 v8 = *(const f16x8*)(inH + (size_t)row_g * DIM + c0);
#pragma unroll
                for (int j = 0; j < 8; ++j) {
                    float v = (float)v8[j] * sScale[c0 + j] + sShift[c0 + j];
                    h8[j] = (f16)fmaxf(v, 0.f);
                }
            } else {
                float4 v0 = *(const float4*)(inF + (size_t)row_g * DIM + c0);
                float4 v1 = *(const float4*)(inF + (size_t)row_g * DIM + c0 + 4);
                h8[0] = (f16)v0.x; h8[1] = (f16)v0.y; h8[2] = (f16)v0.z; h8[3] = (f16)v0.w;
                h8[4] = (f16)v1.x; h8[5] = (f16)v1.y; h8[6] = (f16)v1.z; h8[7] = (f16)v1.w;
            }
            int byte = (r * 256 + c0 * 2) ^ ((r & 7) << 4);
            *(f16x8*)(sA + byte) = h8;
        }
    }
    __syncthreads();

    // ---- MFMA main: 2 products (W-hi, W-lo) ----
    f32x4 accA[4][2], accB[4][2];
#pragma unroll
    for (int rt = 0; rt < 4; ++rt)
#pragma unroll
        for (int ct = 0; ct < 2; ++ct) {
            accA[rt][ct] = (f32x4){0.f, 0.f, 0.f, 0.f};
            accB[rt][ct] = (f32x4){0.f, 0.f, 0.f, 0.f};
        }

#pragma unroll
    for (int rt = 0; rt < 4; ++rt) {
        int row_l = rt * 16 + (l & 15);
        int kb = (l >> 4) * 16;
        f16x8 a[4];
#pragma unroll
        for (int kt = 0; kt < 4; ++kt) {
            int byte = (row_l * 256 + kt * 64 + kb) ^ ((row_l & 7) << 4);
            a[kt] = *(const f16x8*)(sA + byte);
        }
#pragma unroll
        for (int ct = 0; ct < 2; ++ct) {
            f32x4 cA = accA[rt][ct], cB = accB[rt][ct];
#pragma unroll
            for (int kt = 0; kt < 4; ++kt) {
                cA = __builtin_amdgcn_mfma_f32_16x16x32_f16(a[kt], bh[ct][kt], cA, 0, 0, 0);
                cB = __builtin_amdgcn_mfma_f32_16x16x32_f16(a[kt], bl[ct][kt], cB, 0, 0, 0);
            }
            accA[rt][ct] = cA;
            accB[rt][ct] = cB;
        }
    }

    // ---- epilogue: combine, scale by dinv[row], store fp16 ----
    int colw = w * 32 + (l & 15);
#pragma unroll
    for (int rt = 0; rt < 4; ++rt) {
        int row_l = rt * 16 + ((l >> 4) << 2);
#pragma unroll
        for (int reg = 0; reg < 4; ++reg) {
            int gr = row0 + row_l + reg;
            if (gr >= n) continue;
            float dv = dinv[gr];
#pragma unroll
            for (int ct = 0; ct < 2; ++ct) {
                float v = (accA[rt][ct][reg] + accB[rt][ct][reg] * (1.0f / 2048.0f)) * dv;
                out[(size_t)gr * DIM + colw + ct * 16] = (f16)v;
            }
        }
    }
}

// ---------------- fused gather + BN stats (+ pool): 4 waves = 4 nodes/block ----------
// 256-thr blocks: 8 blocks/CU -> full 32 waves/CU residency for the latency-bound
// gather. Wave-per-node, 4-deep predicated edge batch (deg<=16 = 1 round trip).
template <bool POOL>
__global__ __launch_bounds__(256) void k_gs(const f16* __restrict__ hs,
                                            const int* __restrict__ csr_src,
                                            const int* __restrict__ row_ptr,
                                            const float* __restrict__ dinv,
                                            const float* __restrict__ b,
                                            const int* __restrict__ batch,
                                            f16* __restrict__ agg,
                                            float* __restrict__ stats_part,
                                            float* __restrict__ gsum, int n) {
    __shared__ float sSum[4][DIM];
    __shared__ float sSq[4][DIM];
    __shared__ int sSeg[4];

    int t = threadIdx.x;
    int wv = t >> 6, l = t & 63;
    int node = blockIdx.x * 4 + wv;
    int grp = l >> 4;
    int c8 = (l & 15) * 8;
    bool valid = node < n;

    float acc[8] = {};
    int beg = 0, end = 0;
    if (valid) {
        beg = row_ptr[node];
        end = row_ptr[node + 1];
    }
    // 4-deep predicated batch: all loads issue, then accumulate.
    for (int e = beg + grp; e < end; e += 16) {
        bool v1 = e + 4 < end, v2 = e + 8 < end, v3 = e + 12 < end;
        f16x8 a0 = *(const f16x8*)(hs + (size_t)csr_src[e] * DIM + c8);
        f16x8 a1 = {}, a2 = {}, a3 = {};
        if (v1) a1 = *(const f16x8*)(hs + (size_t)csr_src[e + 4] * DIM + c8);
        if (v2) a2 = *(const f16x8*)(hs + (size_t)csr_src[e + 8] * DIM + c8);
        if (v3) a3 = *(const f16x8*)(hs + (size_t)csr_src[e + 12] * DIM + c8);
#pragma unroll
        for (int j = 0; j < 8; ++j)
            acc[j] += ((float)a0[j] + (float)a1[j]) + ((float)a2[j] + (float)a3[j]);
    }
#pragma unroll
    for (int j = 0; j < 8; ++j) {
        acc[j] += __shfl_xor(acc[j], 16, 64);
        acc[j] += __shfl_xor(acc[j], 32, 64);
    }

    if (grp == 0) {
        if (valid) {
            f16x8 hv = *(const f16x8*)(hs + (size_t)node * DIM + c8);
            float dv = dinv[node];
            f32x4 bb0 = *(const f32x4*)(b + c8);
            f32x4 bb1 = *(const f32x4*)(b + c8 + 4);
            float o[8];
#pragma unroll
            for (int j = 0; j < 4; ++j) {
                o[j] = (acc[j] + (float)hv[j]) * dv + bb0[j];
                o[j + 4] = (acc[j + 4] + (float)hv[j + 4]) * dv + bb1[j];
            }
            f16x8 ov;
#pragma unroll
            for (int j = 0; j < 8; ++j) ov[j] = (f16)o[j];
            *(f16x8*)(agg + (size_t)node * DIM + c8) = ov;
            f32x4 s0 = {o[0], o[1], o[2], o[3]}, s1 = {o[4], o[5], o[6], o[7]};
            f32x4 q0 = {o[0]*o[0], o[1]*o[1], o[2]*o[2], o[3]*o[3]};
            f32x4 q1 = {o[4]*o[4], o[5]*o[5], o[6]*o[6], o[7]*o[7]};
            *(f32x4*)&sSum[wv][c8] = s0;
            *(f32x4*)&sSum[wv][c8 + 4] = s1;
            *(f32x4*)&sSq[wv][c8] = q0;
            *(f32x4*)&sSq[wv][c8 + 4] = q1;
            if (POOL && l == 0) sSeg[wv] = batch[node] - batch[0];
        } else {
            f32x4 z = {0.f, 0.f, 0.f, 0.f};
            *(f32x4*)&sSum[wv][c8] = z;
            *(f32x4*)&sSum[wv][c8 + 4] = z;
            *(f32x4*)&sSq[wv][c8] = z;
            *(f32x4*)&sSq[wv][c8 + 4] = z;
            if (POOL && l == 0) sSeg[wv] = -1;
        }
    }
    __syncthreads();

    int shard = (blockIdx.x & (NSHARD - 1)) * 256;
    if (t < 128) {
        float s = sSum[0][t] + sSum[1][t] + sSum[2][t] + sSum[3][t];
        atomicAdd(&stats_part[shard + t], s);
    } else {
        int ch = t - 128;
        float s = sSq[0][ch] + sSq[1][ch] + sSq[2][ch] + sSq[3][ch];
        atomicAdd(&stats_part[shard + 128 + ch], s);
    }

    if (POOL && t < 128) {
        int cur = -1;
        float a = 0.f;
#pragma unroll
        for (int w = 0; w < 4; ++w) {
            int sg = sSeg[w];
            if (sg < 0) continue;
            if (sg != cur) {
                if (cur >= 0) atomicAdd(&gsum[(size_t)cur * DIM + t], a);
                a = 0.f;
                cur = sg;
            }
            a += sSum[w][t];
        }
        if (cur >= 0) atomicAdd(&gsum[(size_t)cur * DIM + t], a);
    }
}

// ---------------- pool finalize: out = mean*scale + shift ----------------
__global__ __launch_bounds__(128) void k_pool_fin(const float* __restrict__ gsum,
                                                  const int* __restrict__ batch,
                                                  const float* __restrict__ stats,
                                                  const float* __restrict__ g,
                                                  const float* __restrict__ be,
                                                  float* __restrict__ out,
                                                  int n, float inv_n) {
    int gseg = blockIdx.x;
    int c = threadIdx.x;
    int b0 = batch[0];
    int target = b0 + gseg;
    int lo = 0, hi = n;
    while (lo < hi) { int mid = (lo + hi) >> 1; if (batch[mid] < target) lo = mid + 1; else hi = mid; }
    int start = lo;
    lo = start; hi = n;
    while (lo < hi) { int mid = (lo + hi) >> 1; if (batch[mid] < target + 1) lo = mid + 1; else hi = mid; }
    int end = lo;
    int cnt = end - start;

    float su = 0.f, sq = 0.f;
    for (int s = 0; s < NSHARD; ++s) {
        su += stats[s * 256 + c];
        sq += stats[s * 256 + 128 + c];
    }
    float mu = su * inv_n;
    float var = sq * inv_n - mu * mu;
    float scale = rsqrtf(var + EPS) * g[c];
    float shift = be[c] - mu * scale;
    float o = 0.f;
    if (cnt > 0) o = (gsum[(size_t)gseg * DIM + c] / (float)cnt) * scale + shift;
    out[(size_t)gseg * DIM + c] = o;
}

// ---------------- launch ----------------
extern "C" void kernel_launch(void* const* d_in, const int* in_sizes, int n_in,
                              void* d_out, int out_size, void* d_ws, size_t ws_size,
                              hipStream_t stream) {
    const float* x = (const float*)d_in[0];
    const int* edge_index = (const int*)d_in[1];
    const int* batch = (const int*)d_in[3];
    const float* W1 = (const float*)d_in[4];
    const float* b1 = (const float*)d_in[5];
    const float* g1 = (const float*)d_in[6];
    const float* be1 = (const float*)d_in[7];
    const float* Wm = (const float*)d_in[8];
    const float* bm = (const float*)d_in[9];
    const float* gm = (const float*)d_in[10];
    const float* bem = (const float*)d_in[11];
    const float* W2 = (const float*)d_in[12];
    const float* b2 = (const float*)d_in[13];
    const float* g2 = (const float*)d_in[14];
    const float* be2 = (const float*)d_in[15];

    int n = in_sizes[0] / DIM;
    int E = in_sizes[1] / 2;
    int G = out_size / DIM;

    const int* srcI = edge_index;
    const int* dstI = edge_index + E;

    char* p = (char*)d_ws;
    f16* bufA = (f16*)p;                p += (size_t)n * DIM * 2;   // hs fp16
    f16* bufB = (f16*)p;                p += (size_t)n * DIM * 2;   // agg fp16
    float* dinv = (float*)p;            p += (size_t)n * 4;
    int* row_ptr = (int*)p;             p += (size_t)(n + 1) * 4;
    int* cursor = (int*)p;              p += (size_t)n * 4;
    int* csr_src = (int*)p;             p += (size_t)E * 4;
    int* bsum = (int*)p;                p += 64 * 4;
    // ---- contiguous zero region ----
    char* zero0 = p;
    int* degi = (int*)p;                p += (size_t)n * 4;
    float* stats3 = (float*)p;          p += 3 * SHARD * 4;
    float* gsum = (float*)p;            p += (size_t)G * DIM * 4;
    size_t zero_bytes = (size_t)(p - zero0);
    // ---- W split buffer ----
    f16* wsplit = (f16*)p;              p += (size_t)3 * 2 * DIM * DIM * 2;

    float* out = (float*)d_out;
    float inv_n = 1.0f / (float)n;
    int nb = (n + 1023) / 1024;  // <= 64 assumed

    // ---- init + CSR build + W split ----
    hipMemsetAsync(zero0, 0, zero_bytes, stream);
    k_prep<<<12 + (E + 255) / 256, 256, 0, stream>>>(dstI, degi, E, W1, Wm, W2, wsplit);
    k_scan_local<<<nb, 256, 0, stream>>>(degi, row_ptr, dinv, bsum, n);
    k_scan_add<<<(n + 255) / 256, 256, 0, stream>>>(row_ptr, cursor, bsum, n, E, nb);
    k_fill<<<(E + 255) / 256, 256, 0, stream>>>(srcI, dstI, cursor, csr_src, E);

    struct Layer { const float *b, *g, *be; };
    Layer L[3] = {{b1, g1, be1}, {bm, gm, bem}, {b2, g2, be2}};

    int mmBlocks = (n + 63) / 64;
    int gsBlocks = (n + 3) / 4;
    for (int l = 0; l < 3; ++l) {
        const f16* wl = wsplit + (size_t)l * 2 * DIM * DIM;
        float* stats_l = stats3 + l * SHARD;
        if (l == 0)
            k_matmul_mfma<false><<<mmBlocks, 256, 0, stream>>>(
                x, nullptr, wl, dinv, nullptr, nullptr, nullptr, inv_n, bufA, n);
        else
            k_matmul_mfma<true><<<mmBlocks, 256, 0, stream>>>(
                nullptr, bufB, wl, dinv, stats3 + (l - 1) * SHARD,
                L[l - 1].g, L[l - 1].be, inv_n, bufA, n);
        if (l < 2)
            k_gs<false><<<gsBlocks, 256, 0, stream>>>(bufA, csr_src, row_ptr, dinv,
                                                      L[l].b, batch, bufB, stats_l,
                                                      nullptr, n);
        else
            k_gs<true><<<gsBlocks, 256, 0, stream>>>(bufA, csr_src, row_ptr, dinv,
                                                     L[l].b, batch, bufB, stats_l,
                                                     gsum, n);
    }

    // pool finalize: mean -> final BN affine
    k_pool_fin<<<G, 128, 0, stream>>>(gsum, batch, stats3 + 2 * SHARD, g2, be2,
                                      out, n, inv_n);
}

// Round 14
// 250.969 us; speedup vs baseline: 1.1365x; 1.0699x over previous
//
#include <hip/hip_runtime.h>

#define DIM 128
constexpr float EPS = 1e-5f;
#define NSHARD 32
#define SHARD (NSHARD * 256)  // floats per layer: 32 shards x (sum[128]+sumsq[128])

typedef _Float16 f16;
typedef __attribute__((ext_vector_type(8))) _Float16 f16x8;
typedef __attribute__((ext_vector_type(4))) float f32x4;

// ---------------- prep: W fp16-transpose (blocks 0..11) + degree count (12..) --------
__global__ __launch_bounds__(256) void k_prep(const int* __restrict__ dst,
                                              int* __restrict__ degi, int E,
                                              const float* __restrict__ W0,
                                              const float* __restrict__ W1,
                                              const float* __restrict__ W2,
                                              f16* __restrict__ wt) {
    if (blockIdx.x < 12) {
        int layer = blockIdx.x >> 2;
        int quarter = blockIdx.x & 3;
        const float* W = layer == 0 ? W0 : (layer == 1 ? W1 : W2);
        f16* hi = wt + (size_t)layer * DIM * DIM;
        for (int idx = quarter * 4096 + threadIdx.x; idx < (quarter + 1) * 4096;
             idx += 256) {
            int k = idx >> 7, c = idx & 127;
            hi[c * DIM + k] = (f16)W[idx];
        }
    } else {
        int e = (blockIdx.x - 12) * 256 + threadIdx.x;
        if (e < E) atomicAdd(&degi[dst[e]], 1);
    }
}

// ---------------- scan pass 1: block-local exclusive scan + fused dinv ----------------
__global__ __launch_bounds__(256) void k_scan_local(const int* __restrict__ degi,
                                                    int* __restrict__ row_ptr,
                                                    float* __restrict__ dinv,
                                                    int* __restrict__ bsum, int n) {
    __shared__ int ws[4];
    int t = threadIdx.x, lane = t & 63, wv = t >> 6;
    int i0 = blockIdx.x * 1024 + t * 4;
    int v[4];
#pragma unroll
    for (int j = 0; j < 4; ++j) {
        int i = i0 + j;
        v[j] = (i < n) ? degi[i] : 0;
        if (i < n) dinv[i] = rsqrtf((float)v[j] + 1.0f);
    }
    int tsum = v[0] + v[1] + v[2] + v[3];
    int sc = tsum;
#pragma unroll
    for (int off = 1; off < 64; off <<= 1) {
        int u = __shfl_up(sc, off, 64);
        if (lane >= off) sc += u;
    }
    if (lane == 63) ws[wv] = sc;
    __syncthreads();
    int woff = 0;
    for (int j = 0; j < wv; ++j) woff += ws[j];
    int run = woff + sc - tsum;
#pragma unroll
    for (int j = 0; j < 4; ++j) {
        int i = i0 + j;
        if (i < n) row_ptr[i] = run;
        run += v[j];
    }
    if (t == 255) bsum[blockIdx.x] = woff + sc;
}

// ---------------- scan pass 2: add block offsets (inline bsum scan), cursor init ------
__global__ __launch_bounds__(256) void k_scan_add(int* __restrict__ row_ptr,
                                                  int* __restrict__ cursor,
                                                  const int* __restrict__ bsum,
                                                  int n, int E, int nb) {
    __shared__ int soff;
    int t = threadIdx.x;
    int seg = blockIdx.x >> 2;
    if (t < 64) {
        int v = (t < nb) ? bsum[t] : 0;
        int sc = v;
#pragma unroll
        for (int off = 1; off < 64; off <<= 1) {
            int u = __shfl_up(sc, off, 64);
            if (t >= off) sc += u;
        }
        if (t == seg) soff = sc - v;
    }
    __syncthreads();
    int i = blockIdx.x * 256 + t;
    if (i < n) {
        int v = row_ptr[i] + soff;
        row_ptr[i] = v;
        cursor[i] = v;
    }
    if (i == 0) row_ptr[n] = E;
}

// ---------------- fill CSR: csr_src grouped by dst ----------------
__global__ void k_fill(const int* __restrict__ src, const int* __restrict__ dst,
                       int* __restrict__ cursor, int* __restrict__ csr_src, int E) {
    int e = blockIdx.x * blockDim.x + threadIdx.x;
    if (e >= E) return;
    int d = dst[e];
    int slot = atomicAdd(&cursor[d], 1);
    csr_src[slot] = src[e];
}

// ---------------- MFMA GEMM: fp16 A x fp16 W, 128-row block (2 x 64-row halves) ------
template <bool PRE_BN>
__global__ __launch_bounds__(256) void k_matmul_mfma(
    const float* __restrict__ inF, const f16* __restrict__ inH,
    const f16* __restrict__ wt, const float* __restrict__ dinv,
    const float* __restrict__ stats, const float* __restrict__ g,
    const float* __restrict__ be, float inv_n, f16* __restrict__ out, int n) {
    __shared__ __align__(16) char sA[64 * 256];
    __shared__ float sScale[DIM], sShift[DIM];

    int t = threadIdx.x;
    int w = t >> 6, l = t & 63;

    if (PRE_BN) {
        if (t < DIM) {
            float su = 0.f, sq = 0.f;
            for (int s = 0; s < NSHARD; ++s) {
                su += stats[s * 256 + t];
                sq += stats[s * 256 + 128 + t];
            }
            float mu = su * inv_n;
            float var = sq * inv_n - mu * mu;
            float sc = rsqrtf(var + EPS) * g[t];
            sScale[t] = sc;
            sShift[t] = be[t] - mu * sc;
        }
        __syncthreads();
    }

    // ---- W fragments, loaded once per block (reused by both halves) ----
    f16x8 bh[2][4];
    {
        int col = w * 32 + (l & 15);
        int ksub = (l >> 4) * 8;
#pragma unroll
        for (int ct = 0; ct < 2; ++ct) {
            int c2 = col + ct * 16;
#pragma unroll
            for (int kt = 0; kt < 4; ++kt)
                bh[ct][kt] = *(const f16x8*)&wt[(size_t)c2 * DIM + kt * 32 + ksub];
        }
    }

#pragma unroll
    for (int half = 0; half < 2; ++half) {
        int row0 = blockIdx.x * 128 + half * 64;
        if (row0 >= n) break;
        if (half == 1) __syncthreads();  // all reads of sA (half 0) done

        // ---- stage A tile (64x128 fp16), XOR-swizzled ----
        {
            int r = t >> 2;
            int row_g = row0 + r;
            if (row_g >= n) row_g = n - 1;
            int cbase = (t & 3) * 32;
#pragma unroll
            for (int o = 0; o < 4; ++o) {
                int c0 = cbase + o * 8;
                f16x8 h8;
                if (PRE_BN) {
                    f16x8 v8 = *(const f16x8*)(inH + (size_t)row_g * DIM + c0);
#pragma unroll
                    for (int j = 0; j < 8; ++j) {
                        float v = (float)v8[j] * sScale[c0 + j] + sShift[c0 + j];
                        h8[j] = (f16)fmaxf(v, 0.f);
                    }
                } else {
                    float4 v0 = *(const float4*)(inF + (size_t)row_g * DIM + c0);
                    float4 v1 = *(const float4*)(inF + (size_t)row_g * DIM + c0 + 4);
                    h8[0] = (f16)v0.x; h8[1] = (f16)v0.y; h8[2] = (f16)v0.z; h8[3] = (f16)v0.w;
                    h8[4] = (f16)v1.x; h8[5] = (f16)v1.y; h8[6] = (f16)v1.z; h8[7] = (f16)v1.w;
                }
                int byte = (r * 256 + c0 * 2) ^ ((r & 7) << 4);
                *(f16x8*)(sA + byte) = h8;
            }
        }
        __syncthreads();

        // ---- MFMA: single product ----
        f32x4 acc[4][2];
#pragma unroll
        for (int rt = 0; rt < 4; ++rt)
#pragma unroll
            for (int ct = 0; ct < 2; ++ct) acc[rt][ct] = (f32x4){0.f, 0.f, 0.f, 0.f};

#pragma unroll
        for (int rt = 0; rt < 4; ++rt) {
            int row_l = rt * 16 + (l & 15);
            int kb = (l >> 4) * 16;
            f16x8 a[4];
#pragma unroll
            for (int kt = 0; kt < 4; ++kt) {
                int byte = (row_l * 256 + kt * 64 + kb) ^ ((row_l & 7) << 4);
                a[kt] = *(const f16x8*)(sA + byte);
            }
#pragma unroll
            for (int ct = 0; ct < 2; ++ct) {
                f32x4 c = acc[rt][ct];
#pragma unroll
                for (int kt = 0; kt < 4; ++kt)
                    c = __builtin_amdgcn_mfma_f32_16x16x32_f16(a[kt], bh[ct][kt], c, 0, 0, 0);
                acc[rt][ct] = c;
            }
        }

        // ---- epilogue: scale by dinv[row], store fp16 ----
        int colw = w * 32 + (l & 15);
#pragma unroll
        for (int rt = 0; rt < 4; ++rt) {
            int row_l = rt * 16 + ((l >> 4) << 2);
#pragma unroll
            for (int reg = 0; reg < 4; ++reg) {
                int gr = row0 + row_l + reg;
                if (gr >= n) continue;
                float dv = dinv[gr];
#pragma unroll
                for (int ct = 0; ct < 2; ++ct)
                    out[(size_t)gr * DIM + colw + ct * 16] = (f16)(acc[rt][ct][reg] * dv);
            }
        }
    }
}

// ---------------- fused gather + BN stats (+ pool): 4 waves = 4 nodes/block ----------
template <bool POOL>
__global__ __launch_bounds__(256) void k_gs(const f16* __restrict__ hs,
                                            const int* __restrict__ csr_src,
                                            const int* __restrict__ row_ptr,
                                            const float* __restrict__ dinv,
                                            const float* __restrict__ b,
                                            const int* __restrict__ batch,
                                            f16* __restrict__ agg,
                                            float* __restrict__ stats_part,
                                            float* __restrict__ gsum, int n) {
    __shared__ float sSum[4][DIM];
    __shared__ float sSq[4][DIM];
    __shared__ int sSeg[4];

    int t = threadIdx.x;
    int wv = t >> 6, l = t & 63;
    int node = blockIdx.x * 4 + wv;
    int grp = l >> 4;
    int c8 = (l & 15) * 8;
    bool valid = node < n;

    // self row issued early (independent of edge chain)
    f16x8 hv = {};
    if (valid && grp == 0) hv = *(const f16x8*)(hs + (size_t)node * DIM + c8);

    float acc[8] = {};
    int beg = 0, end = 0;
    if (valid) {
        beg = row_ptr[node];
        end = row_ptr[node + 1];
    }
    for (int e = beg + grp; e < end; e += 16) {
        bool v1 = e + 4 < end, v2 = e + 8 < end, v3 = e + 12 < end;
        f16x8 a0 = *(const f16x8*)(hs + (size_t)csr_src[e] * DIM + c8);
        f16x8 a1 = {}, a2 = {}, a3 = {};
        if (v1) a1 = *(const f16x8*)(hs + (size_t)csr_src[e + 4] * DIM + c8);
        if (v2) a2 = *(const f16x8*)(hs + (size_t)csr_src[e + 8] * DIM + c8);
        if (v3) a3 = *(const f16x8*)(hs + (size_t)csr_src[e + 12] * DIM + c8);
#pragma unroll
        for (int j = 0; j < 8; ++j)
            acc[j] += ((float)a0[j] + (float)a1[j]) + ((float)a2[j] + (float)a3[j]);
    }
#pragma unroll
    for (int j = 0; j < 8; ++j) {
        acc[j] += __shfl_xor(acc[j], 16, 64);
        acc[j] += __shfl_xor(acc[j], 32, 64);
    }

    if (grp == 0) {
        if (valid) {
            float dv = dinv[node];
            f32x4 bb0 = *(const f32x4*)(b + c8);
            f32x4 bb1 = *(const f32x4*)(b + c8 + 4);
            float o[8];
#pragma unroll
            for (int j = 0; j < 4; ++j) {
                o[j] = (acc[j] + (float)hv[j]) * dv + bb0[j];
                o[j + 4] = (acc[j + 4] + (float)hv[j + 4]) * dv + bb1[j];
            }
            f16x8 ov;
#pragma unroll
            for (int j = 0; j < 8; ++j) ov[j] = (f16)o[j];
            *(f16x8*)(agg + (size_t)node * DIM + c8) = ov;
            f32x4 s0 = {o[0], o[1], o[2], o[3]}, s1 = {o[4], o[5], o[6], o[7]};
            f32x4 q0 = {o[0]*o[0], o[1]*o[1], o[2]*o[2], o[3]*o[3]};
            f32x4 q1 = {o[4]*o[4], o[5]*o[5], o[6]*o[6], o[7]*o[7]};
            *(f32x4*)&sSum[wv][c8] = s0;
            *(f32x4*)&sSum[wv][c8 + 4] = s1;
            *(f32x4*)&sSq[wv][c8] = q0;
            *(f32x4*)&sSq[wv][c8 + 4] = q1;
            if (POOL && l == 0) sSeg[wv] = batch[node] - batch[0];
        } else {
            f32x4 z = {0.f, 0.f, 0.f, 0.f};
            *(f32x4*)&sSum[wv][c8] = z;
            *(f32x4*)&sSum[wv][c8 + 4] = z;
            *(f32x4*)&sSq[wv][c8] = z;
            *(f32x4*)&sSq[wv][c8 + 4] = z;
            if (POOL && l == 0) sSeg[wv] = -1;
        }
    }
    __syncthreads();

    int shard = (blockIdx.x & (NSHARD - 1)) * 256;
    if (t < 128) {
        float s = sSum[0][t] + sSum[1][t] + sSum[2][t] + sSum[3][t];
        atomicAdd(&stats_part[shard + t], s);
    } else {
        int ch = t - 128;
        float s = sSq[0][ch] + sSq[1][ch] + sSq[2][ch] + sSq[3][ch];
        atomicAdd(&stats_part[shard + 128 + ch], s);
    }

    if (POOL && t < 128) {
        int cur = -1;
        float a = 0.f;
#pragma unroll
        for (int w = 0; w < 4; ++w) {
            int sg = sSeg[w];
            if (sg < 0) continue;
            if (sg != cur) {
                if (cur >= 0) atomicAdd(&gsum[(size_t)cur * DIM + t], a);
                a = 0.f;
                cur = sg;
            }
            a += sSum[w][t];
        }
        if (cur >= 0) atomicAdd(&gsum[(size_t)cur * DIM + t], a);
    }
}

// ---------------- pool finalize: out = mean*scale + shift ----------------
__global__ __launch_bounds__(128) void k_pool_fin(const float* __restrict__ gsum,
                                                  const int* __restrict__ batch,
                                                  const float* __restrict__ stats,
                                                  const float* __restrict__ g,
                                                  const float* __restrict__ be,
                                                  float* __restrict__ out,
                                                  int n, float inv_n) {
    int gseg = blockIdx.x;
    int c = threadIdx.x;
    int b0 = batch[0];
    int target = b0 + gseg;
    int lo = 0, hi = n;
    while (lo < hi) { int mid = (lo + hi) >> 1; if (batch[mid] < target) lo = mid + 1; else hi = mid; }
    int start = lo;
    lo = start; hi = n;
    while (lo < hi) { int mid = (lo + hi) >> 1; if (batch[mid] < target + 1) lo = mid + 1; else hi = mid; }
    int end = lo;
    int cnt = end - start;

    float su = 0.f, sq = 0.f;
    for (int s = 0; s < NSHARD; ++s) {
        su += stats[s * 256 + c];
        sq += stats[s * 256 + 128 + c];
    }
    float mu = su * inv_n;
    float var = sq * inv_n - mu * mu;
    float scale = rsqrtf(var + EPS) * g[c];
    float shift = be[c] - mu * scale;
    float o = 0.f;
    if (cnt > 0) o = (gsum[(size_t)gseg * DIM + c] / (float)cnt) * scale + shift;
    out[(size_t)gseg * DIM + c] = o;
}

// ---------------- launch ----------------
extern "C" void kernel_launch(void* const* d_in, const int* in_sizes, int n_in,
                              void* d_out, int out_size, void* d_ws, size_t ws_size,
                              hipStream_t stream) {
    const float* x = (const float*)d_in[0];
    const int* edge_index = (const int*)d_in[1];
    const int* batch = (const int*)d_in[3];
    const float* W1 = (const float*)d_in[4];
    const float* b1 = (const float*)d_in[5];
    const float* g1 = (const float*)d_in[6];
    const float* be1 = (const float*)d_in[7];
    const float* Wm = (const float*)d_in[8];
    const float* bm = (const float*)d_in[9];
    const float* gm = (const float*)d_in[10];
    const float* bem = (const float*)d_in[11];
    const float* W2 = (const float*)d_in[12];
    const float* b2 = (const float*)d_in[13];
    const float* g2 = (const float*)d_in[14];
    const float* be2 = (const float*)d_in[15];

    int n = in_sizes[0] / DIM;
    int E = in_sizes[1] / 2;
    int G = out_size / DIM;

    const int* srcI = edge_index;
    const int* dstI = edge_index + E;

    char* p = (char*)d_ws;
    f16* bufA = (f16*)p;                p += (size_t)n * DIM * 2;   // hs fp16
    f16* bufB = (f16*)p;                p += (size_t)n * DIM * 2;   // agg fp16
    float* dinv = (float*)p;            p += (size_t)n * 4;
    int* row_ptr = (int*)p;             p += (size_t)(n + 1) * 4;
    int* cursor = (int*)p;              p += (size_t)n * 4;
    int* csr_src = (int*)p;             p += (size_t)E * 4;
    int* bsum = (int*)p;                p += 64 * 4;
    // ---- contiguous zero region ----
    char* zero0 = p;
    int* degi = (int*)p;                p += (size_t)n * 4;
    float* stats3 = (float*)p;          p += 3 * SHARD * 4;
    float* gsum = (float*)p;            p += (size_t)G * DIM * 4;
    size_t zero_bytes = (size_t)(p - zero0);
    // ---- W fp16 transposed buffer ----
    f16* wsplit = (f16*)p;              p += (size_t)3 * DIM * DIM * 2;

    float* out = (float*)d_out;
    float inv_n = 1.0f / (float)n;
    int nb = (n + 1023) / 1024;  // <= 64 assumed

    // ---- init + CSR build + W transpose ----
    hipMemsetAsync(zero0, 0, zero_bytes, stream);
    k_prep<<<12 + (E + 255) / 256, 256, 0, stream>>>(dstI, degi, E, W1, Wm, W2, wsplit);
    k_scan_local<<<nb, 256, 0, stream>>>(degi, row_ptr, dinv, bsum, n);
    k_scan_add<<<(n + 255) / 256, 256, 0, stream>>>(row_ptr, cursor, bsum, n, E, nb);
    k_fill<<<(E + 255) / 256, 256, 0, stream>>>(srcI, dstI, cursor, csr_src, E);

    struct Layer { const float *b, *g, *be; };
    Layer L[3] = {{b1, g1, be1}, {bm, gm, bem}, {b2, g2, be2}};

    int mmBlocks = (n + 127) / 128;
    int gsBlocks = (n + 3) / 4;
    for (int l = 0; l < 3; ++l) {
        const f16* wl = wsplit + (size_t)l * DIM * DIM;
        float* stats_l = stats3 + l * SHARD;
        if (l == 0)
            k_matmul_mfma<false><<<mmBlocks, 256, 0, stream>>>(
                x, nullptr, wl, dinv, nullptr, nullptr, nullptr, inv_n, bufA, n);
        else
            k_matmul_mfma<true><<<mmBlocks, 256, 0, stream>>>(
                nullptr, bufB, wl, dinv, stats3 + (l - 1) * SHARD,
                L[l - 1].g, L[l - 1].be, inv_n, bufA, n);
        if (l < 2)
            k_gs<false><<<gsBlocks, 256, 0, stream>>>(bufA, csr_src, row_ptr, dinv,
                                                      L[l].b, batch, bufB, stats_l,
                                                      nullptr, n);
        else
            k_gs<true><<<gsBlocks, 256, 0, stream>>>(bufA, csr_src, row_ptr, dinv,
                                                     L[l].b, batch, bufB, stats_l,
                                                     gsum, n);
    }

    // pool finalize: mean -> final BN affine
    k_pool_fin<<<G, 128, 0, stream>>>(gsum, batch, stats3 + 2 * SHARD, g2, be2,
                                      out, n, inv_n);
}

// Round 15
// 238.916 us; speedup vs baseline: 1.1939x; 1.0505x over previous
//
#include <hip/hip_runtime.h>

#define DIM 128
constexpr float EPS = 1e-5f;
#define NSHARD 32
#define SHARD (NSHARD * 256)  // floats per layer: 32 shards x (sum[128]+sumsq[128])

typedef _Float16 f16;
typedef __attribute__((ext_vector_type(8))) _Float16 f16x8;
typedef __attribute__((ext_vector_type(4))) float f32x4;

// ---------------- prep: W fp16-transpose (blocks 0..11) + degree count (12..) --------
__global__ __launch_bounds__(256) void k_prep(const int* __restrict__ dst,
                                              int* __restrict__ degi, int E,
                                              const float* __restrict__ W0,
                                              const float* __restrict__ W1,
                                              const float* __restrict__ W2,
                                              f16* __restrict__ wt) {
    if (blockIdx.x < 12) {
        int layer = blockIdx.x >> 2;
        int quarter = blockIdx.x & 3;
        const float* W = layer == 0 ? W0 : (layer == 1 ? W1 : W2);
        f16* hi = wt + (size_t)layer * DIM * DIM;
        for (int idx = quarter * 4096 + threadIdx.x; idx < (quarter + 1) * 4096;
             idx += 256) {
            int k = idx >> 7, c = idx & 127;
            hi[c * DIM + k] = (f16)W[idx];
        }
    } else {
        int e = (blockIdx.x - 12) * 256 + threadIdx.x;
        if (e < E) atomicAdd(&degi[dst[e]], 1);
    }
}

// ---------------- scan pass 1: block-local exclusive scan + fused dinv ----------------
__global__ __launch_bounds__(256) void k_scan_local(const int* __restrict__ degi,
                                                    int* __restrict__ row_ptr,
                                                    float* __restrict__ dinv,
                                                    int* __restrict__ bsum, int n) {
    __shared__ int ws[4];
    int t = threadIdx.x, lane = t & 63, wv = t >> 6;
    int i0 = blockIdx.x * 1024 + t * 4;
    int v[4];
#pragma unroll
    for (int j = 0; j < 4; ++j) {
        int i = i0 + j;
        v[j] = (i < n) ? degi[i] : 0;
        if (i < n) dinv[i] = rsqrtf((float)v[j] + 1.0f);
    }
    int tsum = v[0] + v[1] + v[2] + v[3];
    int sc = tsum;
#pragma unroll
    for (int off = 1; off < 64; off <<= 1) {
        int u = __shfl_up(sc, off, 64);
        if (lane >= off) sc += u;
    }
    if (lane == 63) ws[wv] = sc;
    __syncthreads();
    int woff = 0;
    for (int j = 0; j < wv; ++j) woff += ws[j];
    int run = woff + sc - tsum;
#pragma unroll
    for (int j = 0; j < 4; ++j) {
        int i = i0 + j;
        if (i < n) row_ptr[i] = run;
        run += v[j];
    }
    if (t == 255) bsum[blockIdx.x] = woff + sc;
}

// ---------------- scan pass 2: add block offsets (inline bsum scan), cursor init ------
__global__ __launch_bounds__(256) void k_scan_add(int* __restrict__ row_ptr,
                                                  int* __restrict__ cursor,
                                                  const int* __restrict__ bsum,
                                                  int n, int E, int nb) {
    __shared__ int soff;
    int t = threadIdx.x;
    int seg = blockIdx.x >> 2;
    if (t < 64) {
        int v = (t < nb) ? bsum[t] : 0;
        int sc = v;
#pragma unroll
        for (int off = 1; off < 64; off <<= 1) {
            int u = __shfl_up(sc, off, 64);
            if (t >= off) sc += u;
        }
        if (t == seg) soff = sc - v;
    }
    __syncthreads();
    int i = blockIdx.x * 256 + t;
    if (i < n) {
        int v = row_ptr[i] + soff;
        row_ptr[i] = v;
        cursor[i] = v;
    }
    if (i == 0) row_ptr[n] = E;
}

// ---------------- MFMA GEMM body: fp16 A x fp16 W, 128-row block (2 x 64 halves) -----
template <bool PRE_BN>
__device__ __forceinline__ void mm_body(
    const float* __restrict__ inF, const f16* __restrict__ inH,
    const f16* __restrict__ wt, const float* __restrict__ dinv,
    const float* __restrict__ stats, const float* __restrict__ g,
    const float* __restrict__ be, float inv_n, f16* __restrict__ out,
    int n, int bid) {
    __shared__ __align__(16) char sA[64 * 256];
    __shared__ float sScale[DIM], sShift[DIM];

    int t = threadIdx.x;
    int w = t >> 6, l = t & 63;

    if (PRE_BN) {
        if (t < DIM) {
            float su = 0.f, sq = 0.f;
            for (int s = 0; s < NSHARD; ++s) {
                su += stats[s * 256 + t];
                sq += stats[s * 256 + 128 + t];
            }
            float mu = su * inv_n;
            float var = sq * inv_n - mu * mu;
            float sc = rsqrtf(var + EPS) * g[t];
            sScale[t] = sc;
            sShift[t] = be[t] - mu * sc;
        }
        __syncthreads();
    }

    // ---- W fragments, loaded once per block (reused by both halves) ----
    f16x8 bh[2][4];
    {
        int col = w * 32 + (l & 15);
        int ksub = (l >> 4) * 8;
#pragma unroll
        for (int ct = 0; ct < 2; ++ct) {
            int c2 = col + ct * 16;
#pragma unroll
            for (int kt = 0; kt < 4; ++kt)
                bh[ct][kt] = *(const f16x8*)&wt[(size_t)c2 * DIM + kt * 32 + ksub];
        }
    }

#pragma unroll
    for (int half = 0; half < 2; ++half) {
        int row0 = bid * 128 + half * 64;
        if (row0 >= n) break;
        if (half == 1) __syncthreads();  // all reads of sA (half 0) done

        // ---- stage A tile (64x128 fp16), XOR-swizzled ----
        {
            int r = t >> 2;
            int row_g = row0 + r;
            if (row_g >= n) row_g = n - 1;
            int cbase = (t & 3) * 32;
#pragma unroll
            for (int o = 0; o < 4; ++o) {
                int c0 = cbase + o * 8;
                f16x8 h8;
                if (PRE_BN) {
                    f16x8 v8 = *(const f16x8*)(inH + (size_t)row_g * DIM + c0);
#pragma unroll
                    for (int j = 0; j < 8; ++j) {
                        float v = (float)v8[j] * sScale[c0 + j] + sShift[c0 + j];
                        h8[j] = (f16)fmaxf(v, 0.f);
                    }
                } else {
                    float4 v0 = *(const float4*)(inF + (size_t)row_g * DIM + c0);
                    float4 v1 = *(const float4*)(inF + (size_t)row_g * DIM + c0 + 4);
                    h8[0] = (f16)v0.x; h8[1] = (f16)v0.y; h8[2] = (f16)v0.z; h8[3] = (f16)v0.w;
                    h8[4] = (f16)v1.x; h8[5] = (f16)v1.y; h8[6] = (f16)v1.z; h8[7] = (f16)v1.w;
                }
                int byte = (r * 256 + c0 * 2) ^ ((r & 7) << 4);
                *(f16x8*)(sA + byte) = h8;
            }
        }
        __syncthreads();

        // ---- MFMA: single product ----
        f32x4 acc[4][2];
#pragma unroll
        for (int rt = 0; rt < 4; ++rt)
#pragma unroll
            for (int ct = 0; ct < 2; ++ct) acc[rt][ct] = (f32x4){0.f, 0.f, 0.f, 0.f};

#pragma unroll
        for (int rt = 0; rt < 4; ++rt) {
            int row_l = rt * 16 + (l & 15);
            int kb = (l >> 4) * 16;
            f16x8 a[4];
#pragma unroll
            for (int kt = 0; kt < 4; ++kt) {
                int byte = (row_l * 256 + kt * 64 + kb) ^ ((row_l & 7) << 4);
                a[kt] = *(const f16x8*)(sA + byte);
            }
#pragma unroll
            for (int ct = 0; ct < 2; ++ct) {
                f32x4 c = acc[rt][ct];
#pragma unroll
                for (int kt = 0; kt < 4; ++kt)
                    c = __builtin_amdgcn_mfma_f32_16x16x32_f16(a[kt], bh[ct][kt], c, 0, 0, 0);
                acc[rt][ct] = c;
            }
        }

        // ---- epilogue: scale by dinv[row], store fp16 ----
        int colw = w * 32 + (l & 15);
#pragma unroll
        for (int rt = 0; rt < 4; ++rt) {
            int row_l = rt * 16 + ((l >> 4) << 2);
#pragma unroll
            for (int reg = 0; reg < 4; ++reg) {
                int gr = row0 + row_l + reg;
                if (gr >= n) continue;
                float dv = dinv[gr];
#pragma unroll
                for (int ct = 0; ct < 2; ++ct)
                    out[(size_t)gr * DIM + colw + ct * 16] = (f16)(acc[rt][ct][reg] * dv);
            }
        }
    }
}

template <bool PRE_BN>
__global__ __launch_bounds__(256) void k_matmul_mfma(
    const float* __restrict__ inF, const f16* __restrict__ inH,
    const f16* __restrict__ wt, const float* __restrict__ dinv,
    const float* __restrict__ stats, const float* __restrict__ g,
    const float* __restrict__ be, float inv_n, f16* __restrict__ out, int n) {
    mm_body<PRE_BN>(inF, inH, wt, dinv, stats, g, be, inv_n, out, n, blockIdx.x);
}

// ---------------- fused: layer-0 matmul (blocks < mmBlocks) + CSR fill (rest) --------
__global__ __launch_bounds__(256) void k_mm0_fill(
    const float* __restrict__ inF, const f16* __restrict__ wt,
    const float* __restrict__ dinv, f16* __restrict__ out, int n, int mmBlocks,
    const int* __restrict__ src, const int* __restrict__ dst,
    int* __restrict__ cursor, int* __restrict__ csr_src, int E) {
    if ((int)blockIdx.x >= mmBlocks) {
        int e = ((int)blockIdx.x - mmBlocks) * 256 + threadIdx.x;
        if (e < E) {
            int d = dst[e];
            int slot = atomicAdd(&cursor[d], 1);
            csr_src[slot] = src[e];
        }
        return;
    }
    mm_body<false>(inF, nullptr, wt, dinv, nullptr, nullptr, nullptr, 1.0f, out, n,
                   blockIdx.x);
}

// ---------------- fused gather + BN stats (+ pool): 4 waves = 4 nodes/block ----------
// fp16 pairwise-tree accumulation: (a0+a1)+(a2+a3) via v_pk_add_f16 (2 f16 roundings),
// then f32 accumulate. Cuts dependent-path VALU ops 64 -> 28 per 4-edge batch.
template <bool POOL>
__global__ __launch_bounds__(256) void k_gs(const f16* __restrict__ hs,
                                            const int* __restrict__ csr_src,
                                            const int* __restrict__ row_ptr,
                                            const float* __restrict__ dinv,
                                            const float* __restrict__ b,
                                            const int* __restrict__ batch,
                                            f16* __restrict__ agg,
                                            float* __restrict__ stats_part,
                                            float* __restrict__ gsum, int n) {
    __shared__ float sSum[4][DIM];
    __shared__ float sSq[4][DIM];
    __shared__ int sSeg[4];

    int t = threadIdx.x;
    int wv = t >> 6, l = t & 63;
    int node = blockIdx.x * 4 + wv;
    int grp = l >> 4;
    int c8 = (l & 15) * 8;
    bool valid = node < n;

    // self row issued early (independent of edge chain)
    f16x8 hv = {};
    if (valid && grp == 0) hv = *(const f16x8*)(hs + (size_t)node * DIM + c8);

    float acc[8] = {};
    int beg = 0, end = 0;
    if (valid) {
        beg = row_ptr[node];
        end = row_ptr[node + 1];
    }
    for (int e = beg + grp; e < end; e += 16) {
        bool v1 = e + 4 < end, v2 = e + 8 < end, v3 = e + 12 < end;
        f16x8 a0 = *(const f16x8*)(hs + (size_t)csr_src[e] * DIM + c8);
        f16x8 a1 = {}, a2 = {}, a3 = {};
        if (v1) a1 = *(const f16x8*)(hs + (size_t)csr_src[e + 4] * DIM + c8);
        if (v2) a2 = *(const f16x8*)(hs + (size_t)csr_src[e + 8] * DIM + c8);
        if (v3) a3 = *(const f16x8*)(hs + (size_t)csr_src[e + 12] * DIM + c8);
        f16x8 s = (a0 + a1) + (a2 + a3);  // 8x v_pk_add_f16 total, 2 roundings
#pragma unroll
        for (int j = 0; j < 8; ++j) acc[j] += (float)s[j];
    }
#pragma unroll
    for (int j = 0; j < 8; ++j) {
        acc[j] += __shfl_xor(acc[j], 16, 64);
        acc[j] += __shfl_xor(acc[j], 32, 64);
    }

    if (grp == 0) {
        if (valid) {
            float dv = dinv[node];
            f32x4 bb0 = *(const f32x4*)(b + c8);
            f32x4 bb1 = *(const f32x4*)(b + c8 + 4);
            float o[8];
#pragma unroll
            for (int j = 0; j < 4; ++j) {
                o[j] = (acc[j] + (float)hv[j]) * dv + bb0[j];
                o[j + 4] = (acc[j + 4] + (float)hv[j + 4]) * dv + bb1[j];
            }
            f16x8 ov;
#pragma unroll
            for (int j = 0; j < 8; ++j) ov[j] = (f16)o[j];
            *(f16x8*)(agg + (size_t)node * DIM + c8) = ov;
            f32x4 s0 = {o[0], o[1], o[2], o[3]}, s1 = {o[4], o[5], o[6], o[7]};
            f32x4 q0 = {o[0]*o[0], o[1]*o[1], o[2]*o[2], o[3]*o[3]};
            f32x4 q1 = {o[4]*o[4], o[5]*o[5], o[6]*o[6], o[7]*o[7]};
            *(f32x4*)&sSum[wv][c8] = s0;
            *(f32x4*)&sSum[wv][c8 + 4] = s1;
            *(f32x4*)&sSq[wv][c8] = q0;
            *(f32x4*)&sSq[wv][c8 + 4] = q1;
            if (POOL && l == 0) sSeg[wv] = batch[node] - batch[0];
        } else {
            f32x4 z = {0.f, 0.f, 0.f, 0.f};
            *(f32x4*)&sSum[wv][c8] = z;
            *(f32x4*)&sSum[wv][c8 + 4] = z;
            *(f32x4*)&sSq[wv][c8] = z;
            *(f32x4*)&sSq[wv][c8 + 4] = z;
            if (POOL && l == 0) sSeg[wv] = -1;
        }
    }
    __syncthreads();

    int shard = (blockIdx.x & (NSHARD - 1)) * 256;
    if (t < 128) {
        float s = sSum[0][t] + sSum[1][t] + sSum[2][t] + sSum[3][t];
        atomicAdd(&stats_part[shard + t], s);
    } else {
        int ch = t - 128;
        float s = sSq[0][ch] + sSq[1][ch] + sSq[2][ch] + sSq[3][ch];
        atomicAdd(&stats_part[shard + 128 + ch], s);
    }

    if (POOL && t < 128) {
        int cur = -1;
        float a = 0.f;
#pragma unroll
        for (int w = 0; w < 4; ++w) {
            int sg = sSeg[w];
            if (sg < 0) continue;
            if (sg != cur) {
                if (cur >= 0) atomicAdd(&gsum[(size_t)cur * DIM + t], a);
                a = 0.f;
                cur = sg;
            }
            a += sSum[w][t];
        }
        if (cur >= 0) atomicAdd(&gsum[(size_t)cur * DIM + t], a);
    }
}

// ---------------- pool finalize: out = mean*scale + shift ----------------
__global__ __launch_bounds__(128) void k_pool_fin(const float* __restrict__ gsum,
                                                  const int* __restrict__ batch,
                                                  const float* __restrict__ stats,
                                                  const float* __restrict__ g,
                                                  const float* __restrict__ be,
                                                  float* __restrict__ out,
                                                  int n, float inv_n) {
    int gseg = blockIdx.x;
    int c = threadIdx.x;
    int b0 = batch[0];
    int target = b0 + gseg;
    int lo = 0, hi = n;
    while (lo < hi) { int mid = (lo + hi) >> 1; if (batch[mid] < target) lo = mid + 1; else hi = mid; }
    int start = lo;
    lo = start; hi = n;
    while (lo < hi) { int mid = (lo + hi) >> 1; if (batch[mid] < target + 1) lo = mid + 1; else hi = mid; }
    int end = lo;
    int cnt = end - start;

    float su = 0.f, sq = 0.f;
    for (int s = 0; s < NSHARD; ++s) {
        su += stats[s * 256 + c];
        sq += stats[s * 256 + 128 + c];
    }
    float mu = su * inv_n;
    float var = sq * inv_n - mu * mu;
    float scale = rsqrtf(var + EPS) * g[c];
    float shift = be[c] - mu * scale;
    float o = 0.f;
    if (cnt > 0) o = (gsum[(size_t)gseg * DIM + c] / (float)cnt) * scale + shift;
    out[(size_t)gseg * DIM + c] = o;
}

// ---------------- launch ----------------
extern "C" void kernel_launch(void* const* d_in, const int* in_sizes, int n_in,
                              void* d_out, int out_size, void* d_ws, size_t ws_size,
                              hipStream_t stream) {
    const float* x = (const float*)d_in[0];
    const int* edge_index = (const int*)d_in[1];
    const int* batch = (const int*)d_in[3];
    const float* W1 = (const float*)d_in[4];
    const float* b1 = (const float*)d_in[5];
    const float* g1 = (const float*)d_in[6];
    const float* be1 = (const float*)d_in[7];
    const float* Wm = (const float*)d_in[8];
    const float* bm = (const float*)d_in[9];
    const float* gm = (const float*)d_in[10];
    const float* bem = (const float*)d_in[11];
    const float* W2 = (const float*)d_in[12];
    const float* b2 = (const float*)d_in[13];
    const float* g2 = (const float*)d_in[14];
    const float* be2 = (const float*)d_in[15];

    int n = in_sizes[0] / DIM;
    int E = in_sizes[1] / 2;
    int G = out_size / DIM;

    const int* srcI = edge_index;
    const int* dstI = edge_index + E;

    char* p = (char*)d_ws;
    f16* bufA = (f16*)p;                p += (size_t)n * DIM * 2;   // hs fp16
    f16* bufB = (f16*)p;                p += (size_t)n * DIM * 2;   // agg fp16
    float* dinv = (float*)p;            p += (size_t)n * 4;
    int* row_ptr = (int*)p;             p += (size_t)(n + 1) * 4;
    int* cursor = (int*)p;              p += (size_t)n * 4;
    int* csr_src = (int*)p;             p += (size_t)E * 4;
    int* bsum = (int*)p;                p += 64 * 4;
    // ---- contiguous zero region ----
    char* zero0 = p;
    int* degi = (int*)p;                p += (size_t)n * 4;
    float* stats3 = (float*)p;          p += 3 * SHARD * 4;
    float* gsum = (float*)p;            p += (size_t)G * DIM * 4;
    size_t zero_bytes = (size_t)(p - zero0);
    // ---- W fp16 transposed buffer ----
    f16* wsplit = (f16*)p;              p += (size_t)3 * DIM * DIM * 2;

    float* out = (float*)d_out;
    float inv_n = 1.0f / (float)n;
    int nb = (n + 1023) / 1024;  // <= 64 assumed

    // ---- init + CSR build + W transpose ----
    hipMemsetAsync(zero0, 0, zero_bytes, stream);
    k_prep<<<12 + (E + 255) / 256, 256, 0, stream>>>(dstI, degi, E, W1, Wm, W2, wsplit);
    k_scan_local<<<nb, 256, 0, stream>>>(degi, row_ptr, dinv, bsum, n);
    k_scan_add<<<(n + 255) / 256, 256, 0, stream>>>(row_ptr, cursor, bsum, n, E, nb);

    struct Layer { const float *b, *g, *be; };
    Layer L[3] = {{b1, g1, be1}, {bm, gm, bem}, {b2, g2, be2}};

    int mmBlocks = (n + 127) / 128;
    int fillBlocks = (E + 255) / 256;
    int gsBlocks = (n + 3) / 4;

    // layer 0 matmul fused with CSR fill (independent work, one dispatch)
    k_mm0_fill<<<mmBlocks + fillBlocks, 256, 0, stream>>>(
        x, wsplit, dinv, bufA, n, mmBlocks, srcI, dstI, cursor, csr_src, E);
    k_gs<false><<<gsBlocks, 256, 0, stream>>>(bufA, csr_src, row_ptr, dinv,
                                              L[0].b, batch, bufB, stats3,
                                              nullptr, n);

    for (int l = 1; l < 3; ++l) {
        const f16* wl = wsplit + (size_t)l * DIM * DIM;
        float* stats_l = stats3 + l * SHARD;
        k_matmul_mfma<true><<<mmBlocks, 256, 0, stream>>>(
            nullptr, bufB, wl, dinv, stats3 + (l - 1) * SHARD,
            L[l - 1].g, L[l - 1].be, inv_n, bufA, n);
        if (l < 2)
            k_gs<false><<<gsBlocks, 256, 0, stream>>>(bufA, csr_src, row_ptr, dinv,
                                                      L[l].b, batch, bufB, stats_l,
                                                      nullptr, n);
        else
            k_gs<true><<<gsBlocks, 256, 0, stream>>>(bufA, csr_src, row_ptr, dinv,
                                                     L[l].b, batch, bufB, stats_l,
                                                     gsum, n);
    }

    // pool finalize: mean -> final BN affine
    k_pool_fin<<<G, 128, 0, stream>>>(gsum, batch, stats3 + 2 * SHARD, g2, be2,
                                      out, n, inv_n);
}